// Round 1
// baseline (20983.397 us; speedup 1.0000x reference)
//
#include <hip/hip_runtime.h>
#include <cstdint>
#include <cstddef>

#define DDIM 1536
#define NROWS 6272      // B*P*P
#define MBANK 50000
#define NB 8
#define PP 784          // P*P
#define HW 224
#define KS 33
#define PAD 16

// ---------------- row squared norms ----------------
__global__ __launch_bounds__(256) void rownorm_kernel(const float* __restrict__ x,
                                                      float* __restrict__ out, int rows) {
  int row = blockIdx.x;
  if (row >= rows) return;
  const float4* p4 = (const float4*)(x + (size_t)row * DDIM);
  float s = 0.f;
  for (int d = threadIdx.x; d < DDIM / 4; d += 256) {
    float4 v = p4[d];
    s = fmaf(v.x, v.x, s); s = fmaf(v.y, v.y, s);
    s = fmaf(v.z, v.z, s); s = fmaf(v.w, v.w, s);
  }
  for (int off = 32; off; off >>= 1) s += __shfl_down(s, off, 64);
  __shared__ float ls[4];
  int wid = threadIdx.x >> 6, lane = threadIdx.x & 63;
  if (lane == 0) ls[wid] = s;
  __syncthreads();
  if (threadIdx.x == 0) out[row] = ls[0] + ls[1] + ls[2] + ls[3];
}

// ---------------- init best packed ----------------
__global__ void init_best_kernel(unsigned long long* best) {
  int i = blockIdx.x * 256 + threadIdx.x;
  if (i < NROWS) best[i] = ~0ull;
}

// ---------------- fused min-distance GEMM ----------------
// 128x128 tile, 256 threads, each thread 8x8 (quads at +0 / +64)
#define BM 128
#define BN 128
#define DKC 16
#define CSPLIT 16
#define CT ((MBANK + BN - 1) / BN)          // 391
#define CPB ((CT + CSPLIT - 1) / CSPLIT)    // 25

__global__ __launch_bounds__(256) void mindist_kernel(
    const float* __restrict__ A, const float* __restrict__ Bm,
    const float* __restrict__ xnorm, const float* __restrict__ ynorm,
    unsigned long long* __restrict__ best) {
  __shared__ float As[DKC][BM];
  __shared__ float Bs[DKC][BN];
  int t = threadIdx.x;
  int tx = t & 15, ty = t >> 4;
  int row0 = blockIdx.x * BM;

  int rloc[8], cloc[8];
#pragma unroll
  for (int i = 0; i < 4; i++) {
    rloc[i] = ty * 4 + i; rloc[i + 4] = 64 + ty * 4 + i;
    cloc[i] = tx * 4 + i; cloc[i + 4] = 64 + tx * 4 + i;
  }
  float xn[8];
#pragma unroll
  for (int i = 0; i < 8; i++) xn[i] = xnorm[row0 + rloc[i]];

  unsigned long long bestr[8];
#pragma unroll
  for (int i = 0; i < 8; i++) bestr[i] = ~0ull;

  int ct_begin = blockIdx.y * CPB;
  int ct_end = ct_begin + CPB; if (ct_end > CT) ct_end = CT;

  for (int ct = ct_begin; ct < ct_end; ++ct) {
    int c0 = ct * BN;
    float acc[8][8];
#pragma unroll
    for (int i = 0; i < 8; i++)
#pragma unroll
      for (int j = 0; j < 8; j++) acc[i][j] = 0.f;

    for (int dk = 0; dk < DDIM; dk += DKC) {
#pragma unroll
      for (int s = 0; s < 2; ++s) {
        int q = t + s * 256;
        int r = q >> 2, c4 = q & 3;
        float4 va = *(const float4*)(A + (size_t)(row0 + r) * DDIM + dk + c4 * 4);
        As[c4 * 4 + 0][r] = va.x; As[c4 * 4 + 1][r] = va.y;
        As[c4 * 4 + 2][r] = va.z; As[c4 * 4 + 3][r] = va.w;
        int col = c0 + r;
        float4 vb = make_float4(0.f, 0.f, 0.f, 0.f);
        if (col < MBANK) vb = *(const float4*)(Bm + (size_t)col * DDIM + dk + c4 * 4);
        Bs[c4 * 4 + 0][r] = vb.x; Bs[c4 * 4 + 1][r] = vb.y;
        Bs[c4 * 4 + 2][r] = vb.z; Bs[c4 * 4 + 3][r] = vb.w;
      }
      __syncthreads();
#pragma unroll
      for (int k = 0; k < DKC; k++) {
        float4 a0 = *(const float4*)&As[k][ty * 4];
        float4 a1 = *(const float4*)&As[k][64 + ty * 4];
        float4 b0 = *(const float4*)&Bs[k][tx * 4];
        float4 b1 = *(const float4*)&Bs[k][64 + tx * 4];
        float av[8] = {a0.x, a0.y, a0.z, a0.w, a1.x, a1.y, a1.z, a1.w};
        float bv[8] = {b0.x, b0.y, b0.z, b0.w, b1.x, b1.y, b1.z, b1.w};
#pragma unroll
        for (int i = 0; i < 8; i++)
#pragma unroll
          for (int j = 0; j < 8; j++) acc[i][j] = fmaf(av[i], bv[j], acc[i][j]);
      }
      __syncthreads();
    }
    // fold tile into running per-row best
#pragma unroll
    for (int j = 0; j < 8; j++) {
      int col = c0 + cloc[j];
      if (col < MBANK) {
        float yn = ynorm[col];
#pragma unroll
        for (int i = 0; i < 8; i++) {
          float dsq = fmaxf(xn[i] + yn - 2.f * acc[i][j], 0.f);
          unsigned long long pk =
              ((unsigned long long)__float_as_uint(dsq) << 32) | (unsigned)col;
          if (pk < bestr[i]) bestr[i] = pk;
        }
      }
    }
  }
#pragma unroll
  for (int i = 0; i < 8; i++) atomicMin(&best[row0 + rloc[i]], bestr[i]);
}

// ---------------- unpack ----------------
__global__ void unpack_kernel(const unsigned long long* __restrict__ best,
                              float* __restrict__ ps, int* __restrict__ loc) {
  int i = blockIdx.x * 256 + threadIdx.x;
  if (i >= NROWS) return;
  unsigned long long v = best[i];
  ps[i] = sqrtf(__uint_as_float((unsigned)(v >> 32)));
  loc[i] = (int)(v & 0xffffffffu);
}

// ---------------- per-batch argmax ----------------
__global__ __launch_bounds__(256) void argmax_kernel(const float* __restrict__ ps,
                                                     const int* __restrict__ loc,
                                                     float* __restrict__ bscore,
                                                     int* __restrict__ bfrow,
                                                     int* __restrict__ bnn) {
  int b = blockIdx.x, t = threadIdx.x;
  unsigned long long bp = 0;
  for (int p = t; p < PP; p += 256) {
    unsigned long long pk = ((unsigned long long)__float_as_uint(ps[b * PP + p]) << 32) |
                            (unsigned)(0xffffffffu - (unsigned)p);
    if (pk > bp) bp = pk;
  }
  for (int off = 32; off; off >>= 1) {
    unsigned long long o = __shfl_down(bp, off, 64);
    if (o > bp) bp = o;
  }
  __shared__ unsigned long long ls[4];
  int wid = t >> 6, lane = t & 63;
  if (lane == 0) ls[wid] = bp;
  __syncthreads();
  if (t == 0) {
    for (int w = 1; w < 4; w++) if (ls[w] > ls[0]) ls[0] = ls[w];
    unsigned p = 0xffffffffu - (unsigned)(ls[0] & 0xffffffffu);
    bscore[b] = __uint_as_float((unsigned)(ls[0] >> 32));
    bfrow[b] = b * PP + (int)p;
    bnn[b] = loc[b * PP + (int)p];
  }
}

// ---------------- d2: nn_sample vs memory bank ----------------
__global__ __launch_bounds__(256) void d2_kernel(const float* __restrict__ mem,
                                                 const float* __restrict__ ynorm,
                                                 const int* __restrict__ bnn,
                                                 float* __restrict__ d2) {
  __shared__ float nn8[NB][DDIM];
  __shared__ float nnorm[NB];
  for (int e = threadIdx.x; e < NB * DDIM; e += 256) {
    int b = e / DDIM, d = e % DDIM;
    nn8[b][d] = mem[(size_t)bnn[b] * DDIM + d];
  }
  if (threadIdx.x < NB) nnorm[threadIdx.x] = ynorm[bnn[threadIdx.x]];
  __syncthreads();
  int wid = threadIdx.x >> 6, lane = threadIdx.x & 63;
  int gw = blockIdx.x * 4 + wid;
  int nw = gridDim.x * 4;
  for (int m = gw; m < MBANK; m += nw) {
    const float4* mp4 = (const float4*)(mem + (size_t)m * DDIM);
    float acc[NB];
#pragma unroll
    for (int b = 0; b < NB; b++) acc[b] = 0.f;
    for (int d4 = lane; d4 < DDIM / 4; d4 += 64) {
      float4 v = mp4[d4];
#pragma unroll
      for (int b = 0; b < NB; b++) {
        float4 w = *(const float4*)&nn8[b][d4 * 4];
        acc[b] = fmaf(v.x, w.x, acc[b]); acc[b] = fmaf(v.y, w.y, acc[b]);
        acc[b] = fmaf(v.z, w.z, acc[b]); acc[b] = fmaf(v.w, w.w, acc[b]);
      }
    }
    float yn = ynorm[m];
#pragma unroll
    for (int b = 0; b < NB; b++) {
      float r = acc[b];
      for (int off = 32; off; off >>= 1) r += __shfl_down(r, off, 64);
      if (lane == 0) d2[(size_t)b * MBANK + m] = sqrtf(fmaxf(nnorm[b] + yn - 2.f * r, 0.f));
    }
  }
}

// ---------------- top-9 + softmax weight + pred score ----------------
__global__ __launch_bounds__(256) void topk_kernel(
    const float* __restrict__ emb, const float* __restrict__ mem,
    const float* __restrict__ xnorm, const float* __restrict__ ynorm,
    float* __restrict__ d2, const float* __restrict__ bscore,
    const int* __restrict__ bfrow, float* __restrict__ pred) {
  int b = blockIdx.x, t = threadIdx.x;
  __shared__ unsigned long long lred[4];
  __shared__ float fred[4];
  __shared__ int supp[9];
  __shared__ float d3s[9];
  float* row = d2 + (size_t)b * MBANK;
  for (int k = 0; k < 9; k++) {
    unsigned long long bp = ~0ull;
    for (int m = t; m < MBANK; m += 256) {
      unsigned long long pk = ((unsigned long long)__float_as_uint(row[m]) << 32) | (unsigned)m;
      if (pk < bp) bp = pk;
    }
    for (int off = 32; off; off >>= 1) {
      unsigned long long o = __shfl_down(bp, off, 64);
      if (o < bp) bp = o;
    }
    int wid = t >> 6, lane = t & 63;
    if (lane == 0) lred[wid] = bp;
    __syncthreads();
    if (t == 0) {
      for (int w = 1; w < 4; w++) if (lred[w] < lred[0]) lred[0] = lred[w];
      int idx = (int)(lred[0] & 0xffffffffu);
      supp[k] = idx;
      row[idx] = __uint_as_float(0x7f800000u);  // +inf, exclude from later passes
    }
    __syncthreads();
  }
  int frow = bfrow[b];
  const float* x = emb + (size_t)frow * DDIM;
  float xnv = xnorm[frow];
  for (int k = 0; k < 9; k++) {
    const float* y = mem + (size_t)supp[k] * DDIM;
    float s = 0.f;
    for (int d = t; d < DDIM; d += 256) s = fmaf(x[d], y[d], s);
    for (int off = 32; off; off >>= 1) s += __shfl_down(s, off, 64);
    if ((t & 63) == 0) fred[t >> 6] = s;
    __syncthreads();
    if (t == 0) {
      float dot = fred[0] + fred[1] + fred[2] + fred[3];
      d3s[k] = sqrtf(fmaxf(xnv - 2.f * dot + ynorm[supp[k]], 0.f));
    }
    __syncthreads();
  }
  if (t == 0) {
    float mx = d3s[0];
    for (int k = 1; k < 9; k++) mx = fmaxf(mx, d3s[k]);
    float sum = 0.f;
    for (int k = 0; k < 9; k++) sum += expf(d3s[k] - mx);
    float w = 1.f - expf(d3s[0] - mx) / sum;
    pred[b] = w * bscore[b];
  }
}

// ---------------- gaussian weights ----------------
__global__ void gauss_kernel(float* __restrict__ g) {
  __shared__ float tmp[KS];
  int t = threadIdx.x;
  if (t < KS) {
    float x = (float)t - (float)(KS - 1) * 0.5f;
    tmp[t] = __expf(-(x * x) / 32.0f);  // 2*sigma^2 = 32
  }
  __syncthreads();
  if (t == 0) {
    float s = 0.f;
    for (int j = 0; j < KS; j++) s += tmp[j];
    for (int j = 0; j < KS; j++) g[j] = tmp[j] / s;
  }
}

// ---------------- bilinear resize 28 -> 224 (half-pixel, edge clamp) ----------------
__global__ __launch_bounds__(256) void resize_kernel(const float* __restrict__ ps,
                                                     float* __restrict__ out) {
  int idx = blockIdx.x * 256 + threadIdx.x;
  if (idx >= NB * HW * HW) return;
  int x = idx % HW, y = (idx / HW) % HW, b = idx / (HW * HW);
  float sx = (x + 0.5f) * 0.125f - 0.5f;
  float sy = (y + 0.5f) * 0.125f - 0.5f;
  int x0 = (int)floorf(sx), y0 = (int)floorf(sy);
  float fx = sx - x0, fy = sy - y0;
  int x0c = min(max(x0, 0), 27), x1c = min(max(x0 + 1, 0), 27);
  int y0c = min(max(y0, 0), 27), y1c = min(max(y0 + 1, 0), 27);
  const float* p = ps + b * PP;
  float v00 = p[y0c * 28 + x0c], v01 = p[y0c * 28 + x1c];
  float v10 = p[y1c * 28 + x0c], v11 = p[y1c * 28 + x1c];
  out[idx] = v00 * (1.f - fy) * (1.f - fx) + v01 * (1.f - fy) * fx +
             v10 * fy * (1.f - fx) + v11 * fy * fx;
}

// ---------------- separable gaussian blur with reflect padding ----------------
__device__ __forceinline__ int reflect224(int i) {
  if (i < 0) i = -i;
  if (i > 223) i = 446 - i;
  return i;
}

__global__ __launch_bounds__(256) void blurv_kernel(const float* __restrict__ in,
                                                    const float* __restrict__ g,
                                                    float* __restrict__ out) {
  __shared__ float gk[KS];
  if (threadIdx.x < KS) gk[threadIdx.x] = g[threadIdx.x];
  __syncthreads();
  int idx = blockIdx.x * 256 + threadIdx.x;
  if (idx >= NB * HW * HW) return;
  int x = idx % HW, y = (idx / HW) % HW, b = idx / (HW * HW);
  const float* base = in + (size_t)b * HW * HW;
  float s = 0.f;
#pragma unroll
  for (int j = 0; j < KS; j++) {
    int yy = reflect224(y - PAD + j);
    s = fmaf(gk[j], base[yy * HW + x], s);
  }
  out[idx] = s;
}

__global__ __launch_bounds__(256) void blurh_kernel(const float* __restrict__ in,
                                                    const float* __restrict__ g,
                                                    float* __restrict__ out) {
  __shared__ float gk[KS];
  if (threadIdx.x < KS) gk[threadIdx.x] = g[threadIdx.x];
  __syncthreads();
  int idx = blockIdx.x * 256 + threadIdx.x;
  if (idx >= NB * HW * HW) return;
  int x = idx % HW, y = (idx / HW) % HW, b = idx / (HW * HW);
  const float* base = in + (size_t)b * HW * HW;
  float s = 0.f;
#pragma unroll
  for (int j = 0; j < KS; j++) {
    int xx = reflect224(x - PAD + j);
    s = fmaf(gk[j], base[y * HW + xx], s);
  }
  out[idx] = s;
}

// ---------------- host ----------------
extern "C" void kernel_launch(void* const* d_in, const int* in_sizes, int n_in,
                              void* d_out, int out_size, void* d_ws, size_t ws_size,
                              hipStream_t stream) {
  const float* emb = (const float*)d_in[0];
  const float* mem = (const float*)d_in[1];
  float* out = (float*)d_out;

  char* ws = (char*)d_ws;
  size_t off = 0;
  auto alloc = [&](size_t bytes) -> void* {
    void* p = ws + off;
    off += (bytes + 255) & ~(size_t)255;
    return p;
  };
  float* ynorm = (float*)alloc(MBANK * 4);
  float* xnorm = (float*)alloc(NROWS * 4);
  unsigned long long* best = (unsigned long long*)alloc(NROWS * 8);
  float* ps = (float*)alloc(NROWS * 4);
  int* loc = (int*)alloc(NROWS * 4);
  float* bscore = (float*)alloc(NB * 4);
  int* bfrow = (int*)alloc(NB * 4);
  int* bnn = (int*)alloc(NB * 4);
  float* d2 = (float*)alloc((size_t)NB * MBANK * 4);
  float* g = (float*)alloc(KS * 4);
  float* rsz = (float*)alloc((size_t)NB * HW * HW * 4);
  float* tmp = (float*)alloc((size_t)NB * HW * HW * 4);

  rownorm_kernel<<<MBANK, 256, 0, stream>>>(mem, ynorm, MBANK);
  rownorm_kernel<<<NROWS, 256, 0, stream>>>(emb, xnorm, NROWS);
  init_best_kernel<<<(NROWS + 255) / 256, 256, 0, stream>>>(best);
  mindist_kernel<<<dim3(NROWS / BM, CSPLIT), 256, 0, stream>>>(emb, mem, xnorm, ynorm, best);
  unpack_kernel<<<(NROWS + 255) / 256, 256, 0, stream>>>(best, ps, loc);
  argmax_kernel<<<NB, 256, 0, stream>>>(ps, loc, bscore, bfrow, bnn);
  d2_kernel<<<400, 256, 0, stream>>>(mem, ynorm, bnn, d2);
  topk_kernel<<<NB, 256, 0, stream>>>(emb, mem, xnorm, ynorm, d2, bscore, bfrow,
                                      out + (size_t)NB * HW * HW);
  gauss_kernel<<<1, 64, 0, stream>>>(g);
  resize_kernel<<<(NB * HW * HW + 255) / 256, 256, 0, stream>>>(ps, rsz);
  blurv_kernel<<<(NB * HW * HW + 255) / 256, 256, 0, stream>>>(rsz, g, tmp);
  blurh_kernel<<<(NB * HW * HW + 255) / 256, 256, 0, stream>>>(tmp, g, out);
}

// Round 2
// 2797.977 us; speedup vs baseline: 7.4995x; 7.4995x over previous
//
#include <hip/hip_runtime.h>
#include <cstdint>
#include <cstddef>

#define DDIM 1536
#define NROWS 6272      // B*P*P
#define MBANK 50000
#define NPAD 50048      // padded to multiple of 128
#define NB 8
#define PP 784          // P*P
#define HW 224
#define KS 33
#define PAD 16
#define CSPLIT 16
#define CT391 391       // ceil(50000/128)

typedef __attribute__((ext_vector_type(8))) short short8v;
typedef __attribute__((ext_vector_type(4))) float floatx4;

// ---------------- row squared norms ----------------
__global__ __launch_bounds__(256) void rownorm_kernel(const float* __restrict__ x,
                                                      float* __restrict__ out, int rows) {
  int row = blockIdx.x;
  if (row >= rows) return;
  const float4* p4 = (const float4*)(x + (size_t)row * DDIM);
  float s = 0.f;
  for (int d = threadIdx.x; d < DDIM / 4; d += 256) {
    float4 v = p4[d];
    s = fmaf(v.x, v.x, s); s = fmaf(v.y, v.y, s);
    s = fmaf(v.z, v.z, s); s = fmaf(v.w, v.w, s);
  }
  for (int off = 32; off; off >>= 1) s += __shfl_down(s, off, 64);
  __shared__ float ls[4];
  int wid = threadIdx.x >> 6, lane = threadIdx.x & 63;
  if (lane == 0) ls[wid] = s;
  __syncthreads();
  if (threadIdx.x == 0) out[row] = ls[0] + ls[1] + ls[2] + ls[3];
}

// ---------------- fp32 -> bf16 convert (RNE), zero-pad tail ----------------
__device__ __forceinline__ unsigned short f2bf(float f) {
  unsigned u = __float_as_uint(f);
  return (unsigned short)((u + 0x7fffu + ((u >> 16) & 1u)) >> 16);
}

__global__ __launch_bounds__(256) void convert_kernel(const float* __restrict__ in,
                                                      unsigned short* __restrict__ out,
                                                      long valid4, long total4) {
  long i = (long)blockIdx.x * 256 + threadIdx.x;
  long stride = (long)gridDim.x * 256;
  for (; i < total4; i += stride) {
    ushort4 o;
    if (i < valid4) {
      float4 v = ((const float4*)in)[i];
      o.x = f2bf(v.x); o.y = f2bf(v.y); o.z = f2bf(v.z); o.w = f2bf(v.w);
    } else {
      o.x = o.y = o.z = o.w = 0;
    }
    ((ushort4*)out)[i] = o;
  }
}

// ---------------- init u64 buffer to ~0 ----------------
__global__ void init_u64_kernel(unsigned long long* p, int n) {
  int i = blockIdx.x * 256 + threadIdx.x;
  if (i < n) p[i] = ~0ull;
}

// ============== MFMA bf16 min-distance GEMM (fast path) ==============
// 128x128 tile, BK=32, 4 waves, global_load_lds staging, XOR-swizzled reads.
__global__ __launch_bounds__(256, 2) void mindist_mfma_kernel(
    const unsigned short* __restrict__ Ah, const unsigned short* __restrict__ Bh,
    const float* __restrict__ xnorm, const float* __restrict__ ynorm,
    unsigned long long* __restrict__ cand) {
  __shared__ unsigned short As[2][128 * 32];
  __shared__ unsigned short Bs[2][128 * 32];
  int t = threadIdx.x;
  int lane = t & 63, wave = t >> 6;
  int wr = wave >> 1, wc = wave & 1;
  int l15 = lane & 15, g = lane >> 4;
  int row0 = blockIdx.x * 128;
  int cs = blockIdx.y;
  int ss = g ^ ((l15 >> 1) & 3);  // read-side swizzle slot (independent of m/wr)

  float xn[4][4];
#pragma unroll
  for (int m = 0; m < 4; m++)
#pragma unroll
    for (int q = 0; q < 4; q++)
      xn[m][q] = xnorm[row0 + wr * 64 + m * 16 + g * 4 + q];

  unsigned long long bestr[16];
#pragma unroll
  for (int i = 0; i < 16; i++) bestr[i] = ~0ull;

  // balanced col-tile range for this colsplit
  int ct_begin = cs * 24 + (cs < 7 ? cs : 7);
  int ct_end = ct_begin + 24 + (cs < 7 ? 1 : 0);

// staging: thread covers flat 8-bf16 chunk f = t + i*256 of the 128x32 tile;
// LDS linear dest, pre-swizzled global source: sw = (f&3) ^ ((f>>3)&3)
#define STAGE(buf, kk, c0)                                                               \
  {                                                                                      \
    _Pragma("unroll") for (int i = 0; i < 2; i++) {                                      \
      int f = t + i * 256;                                                               \
      int r = f >> 2;                                                                    \
      int sw = (f & 3) ^ ((f >> 3) & 3);                                                 \
      const unsigned short* ga = Ah + (size_t)(row0 + r) * DDIM + (kk) + sw * 8;         \
      __builtin_amdgcn_global_load_lds(                                                  \
          (const __attribute__((address_space(1))) void*)ga,                             \
          (__attribute__((address_space(3))) void*)((char*)&As[buf][0] +                 \
                                                    (i * 4 + wave) * 1024),              \
          16, 0, 0);                                                                     \
      const unsigned short* gb = Bh + (size_t)((c0) + r) * DDIM + (kk) + sw * 8;         \
      __builtin_amdgcn_global_load_lds(                                                  \
          (const __attribute__((address_space(1))) void*)gb,                             \
          (__attribute__((address_space(3))) void*)((char*)&Bs[buf][0] +                 \
                                                    (i * 4 + wave) * 1024),              \
          16, 0, 0);                                                                     \
    }                                                                                    \
  }

  for (int ct = ct_begin; ct < ct_end; ++ct) {
    int c0 = ct * 128;
    floatx4 acc[4][4];
    floatx4 zz = {0.f, 0.f, 0.f, 0.f};
#pragma unroll
    for (int m = 0; m < 4; m++)
#pragma unroll
      for (int n = 0; n < 4; n++) acc[m][n] = zz;

    STAGE(0, 0, c0);
    for (int ks = 0; ks < 48; ks++) {
      __syncthreads();  // compiler emits vmcnt(0) drain before barrier
      int buf = ks & 1;
      if (ks < 47) STAGE(buf ^ 1, (ks + 1) * 32, c0);
      short8v a[4], b[4];
#pragma unroll
      for (int m = 0; m < 4; m++) {
        int r = wr * 64 + m * 16 + l15;
        a[m] = *(const short8v*)&As[buf][r * 32 + ss * 8];
      }
#pragma unroll
      for (int n = 0; n < 4; n++) {
        int r = wc * 64 + n * 16 + l15;
        b[n] = *(const short8v*)&Bs[buf][r * 32 + ss * 8];
      }
#pragma unroll
      for (int m = 0; m < 4; m++)
#pragma unroll
        for (int n = 0; n < 4; n++)
          acc[m][n] = __builtin_amdgcn_mfma_f32_16x16x32_bf16(a[m], b[n], acc[m][n], 0, 0, 0);
    }
    // fold tile into running per-row best (approx dsq, packed with col)
#pragma unroll
    for (int n = 0; n < 4; n++) {
      int col = c0 + wc * 64 + n * 16 + l15;
      if (col < MBANK) {
        float yn = ynorm[col];
#pragma unroll
        for (int m = 0; m < 4; m++)
#pragma unroll
          for (int q = 0; q < 4; q++) {
            float dsq = fmaxf(xn[m][q] + yn - 2.f * acc[m][n][q], 0.f);
            unsigned long long pk =
                ((unsigned long long)__float_as_uint(dsq) << 32) | (unsigned)col;
            int idx = m * 4 + q;
            if (pk < bestr[idx]) bestr[idx] = pk;
          }
      }
    }
  }
  // reduce across the 16 lanes sharing each row
#pragma unroll
  for (int i = 0; i < 16; i++) {
#pragma unroll
    for (int mask = 1; mask <= 8; mask <<= 1) {
      unsigned long long o = __shfl_xor(bestr[i], mask, 64);
      if (o < bestr[i]) bestr[i] = o;
    }
  }
  if (l15 == 0) {
#pragma unroll
    for (int i = 0; i < 16; i++) {
      int m = i >> 2, q = i & 3;
      int row = row0 + wr * 64 + m * 16 + g * 4 + q;
      atomicMin(&cand[(size_t)row * CSPLIT + cs], bestr[i]);
    }
  }
#undef STAGE
}

// ---------------- fp32 re-rank of the 16 per-colsplit winners ----------------
__global__ __launch_bounds__(256) void rerank_kernel(
    const float* __restrict__ emb, const float* __restrict__ mem,
    const float* __restrict__ xnorm, const float* __restrict__ ynorm,
    const unsigned long long* __restrict__ cand, float* __restrict__ ps) {
  int row = blockIdx.x;
  int t = threadIdx.x, lane = t & 63, wave = t >> 6;
  __shared__ float xrow[DDIM];
  __shared__ unsigned long long cmin[4];
  for (int d = t; d < DDIM / 4; d += 256)
    ((float4*)xrow)[d] = ((const float4*)(emb + (size_t)row * DDIM))[d];
  __syncthreads();
  float xnv = xnorm[row];
  unsigned long long best = ~0ull;
  for (int ci = wave; ci < CSPLIT; ci += 4) {
    int col = (int)(cand[(size_t)row * CSPLIT + ci] & 0xffffffffu);
    const float4* yp = (const float4*)(mem + (size_t)col * DDIM);
    float s = 0.f;
    for (int d = lane; d < DDIM / 4; d += 64) {
      float4 v = yp[d];
      float4 x = ((const float4*)xrow)[d];
      s = fmaf(v.x, x.x, s); s = fmaf(v.y, x.y, s);
      s = fmaf(v.z, x.z, s); s = fmaf(v.w, x.w, s);
    }
    for (int off = 32; off; off >>= 1) s += __shfl_down(s, off, 64);
    if (lane == 0) {
      float dsq = fmaxf(xnv + ynorm[col] - 2.f * s, 0.f);
      unsigned long long pk =
          ((unsigned long long)__float_as_uint(dsq) << 32) | (unsigned)col;
      if (pk < best) best = pk;
    }
  }
  if (lane == 0) cmin[wave] = best;
  __syncthreads();
  if (t == 0) {
    for (int w = 1; w < 4; w++)
      if (cmin[w] < cmin[0]) cmin[0] = cmin[w];
    ps[row] = sqrtf(__uint_as_float((unsigned)(cmin[0] >> 32)));
  }
}

// ============== fallback fp32 min-distance GEMM (old path) ==============
#define BM 128
#define BN 128
#define DKC 16
#define FCT ((MBANK + BN - 1) / BN)
#define FCPB ((FCT + CSPLIT - 1) / CSPLIT)

__global__ __launch_bounds__(256) void mindist_kernel(
    const float* __restrict__ A, const float* __restrict__ Bm,
    const float* __restrict__ xnorm, const float* __restrict__ ynorm,
    unsigned long long* __restrict__ best) {
  __shared__ float Asf[DKC][BM];
  __shared__ float Bsf[DKC][BN];
  int t = threadIdx.x;
  int tx = t & 15, ty = t >> 4;
  int row0 = blockIdx.x * BM;
  int rloc[8], cloc[8];
#pragma unroll
  for (int i = 0; i < 4; i++) {
    rloc[i] = ty * 4 + i; rloc[i + 4] = 64 + ty * 4 + i;
    cloc[i] = tx * 4 + i; cloc[i + 4] = 64 + tx * 4 + i;
  }
  float xnv[8];
#pragma unroll
  for (int i = 0; i < 8; i++) xnv[i] = xnorm[row0 + rloc[i]];
  unsigned long long bestr[8];
#pragma unroll
  for (int i = 0; i < 8; i++) bestr[i] = ~0ull;
  int ct_begin = blockIdx.y * FCPB;
  int ct_end = ct_begin + FCPB; if (ct_end > FCT) ct_end = FCT;
  for (int ct = ct_begin; ct < ct_end; ++ct) {
    int c0 = ct * BN;
    float acc[8][8];
#pragma unroll
    for (int i = 0; i < 8; i++)
#pragma unroll
      for (int j = 0; j < 8; j++) acc[i][j] = 0.f;
    for (int dk = 0; dk < DDIM; dk += DKC) {
#pragma unroll
      for (int s = 0; s < 2; ++s) {
        int q = t + s * 256;
        int r = q >> 2, c4 = q & 3;
        float4 va = *(const float4*)(A + (size_t)(row0 + r) * DDIM + dk + c4 * 4);
        Asf[c4 * 4 + 0][r] = va.x; Asf[c4 * 4 + 1][r] = va.y;
        Asf[c4 * 4 + 2][r] = va.z; Asf[c4 * 4 + 3][r] = va.w;
        int col = c0 + r;
        float4 vb = make_float4(0.f, 0.f, 0.f, 0.f);
        if (col < MBANK) vb = *(const float4*)(Bm + (size_t)col * DDIM + dk + c4 * 4);
        Bsf[c4 * 4 + 0][r] = vb.x; Bsf[c4 * 4 + 1][r] = vb.y;
        Bsf[c4 * 4 + 2][r] = vb.z; Bsf[c4 * 4 + 3][r] = vb.w;
      }
      __syncthreads();
#pragma unroll
      for (int k = 0; k < DKC; k++) {
        float4 a0 = *(const float4*)&Asf[k][ty * 4];
        float4 a1 = *(const float4*)&Asf[k][64 + ty * 4];
        float4 b0 = *(const float4*)&Bsf[k][tx * 4];
        float4 b1 = *(const float4*)&Bsf[k][64 + tx * 4];
        float av[8] = {a0.x, a0.y, a0.z, a0.w, a1.x, a1.y, a1.z, a1.w};
        float bv[8] = {b0.x, b0.y, b0.z, b0.w, b1.x, b1.y, b1.z, b1.w};
#pragma unroll
        for (int i = 0; i < 8; i++)
#pragma unroll
          for (int j = 0; j < 8; j++) acc[i][j] = fmaf(av[i], bv[j], acc[i][j]);
      }
      __syncthreads();
    }
#pragma unroll
    for (int j = 0; j < 8; j++) {
      int col = c0 + cloc[j];
      if (col < MBANK) {
        float yn = ynorm[col];
#pragma unroll
        for (int i = 0; i < 8; i++) {
          float dsq = fmaxf(xnv[i] + yn - 2.f * acc[i][j], 0.f);
          unsigned long long pk =
              ((unsigned long long)__float_as_uint(dsq) << 32) | (unsigned)col;
          if (pk < bestr[i]) bestr[i] = pk;
        }
      }
    }
  }
#pragma unroll
  for (int i = 0; i < 8; i++) atomicMin(&best[row0 + rloc[i]], bestr[i]);
}

__global__ void unpack_kernel(const unsigned long long* __restrict__ best,
                              float* __restrict__ ps, int* __restrict__ loc) {
  int i = blockIdx.x * 256 + threadIdx.x;
  if (i >= NROWS) return;
  unsigned long long v = best[i];
  ps[i] = sqrtf(__uint_as_float((unsigned)(v >> 32)));
  loc[i] = (int)(v & 0xffffffffu);
}

// ---------------- per-batch argmax (loc optional) ----------------
__global__ __launch_bounds__(256) void argmax_kernel(const float* __restrict__ ps,
                                                     const int* __restrict__ loc,
                                                     float* __restrict__ bscore,
                                                     int* __restrict__ bfrow,
                                                     int* __restrict__ bnn) {
  int b = blockIdx.x, t = threadIdx.x;
  unsigned long long bp = 0;
  for (int p = t; p < PP; p += 256) {
    unsigned long long pk = ((unsigned long long)__float_as_uint(ps[b * PP + p]) << 32) |
                            (unsigned)(0xffffffffu - (unsigned)p);
    if (pk > bp) bp = pk;
  }
  for (int off = 32; off; off >>= 1) {
    unsigned long long o = __shfl_down(bp, off, 64);
    if (o > bp) bp = o;
  }
  __shared__ unsigned long long ls[4];
  int wid = t >> 6, lane = t & 63;
  if (lane == 0) ls[wid] = bp;
  __syncthreads();
  if (t == 0) {
    for (int w = 1; w < 4; w++) if (ls[w] > ls[0]) ls[0] = ls[w];
    unsigned p = 0xffffffffu - (unsigned)(ls[0] & 0xffffffffu);
    bscore[b] = __uint_as_float((unsigned)(ls[0] >> 32));
    bfrow[b] = b * PP + (int)p;
    if (loc) bnn[b] = loc[b * PP + (int)p];
  }
}

// ---------------- exact fp32 argmin over bank for the 8 max-patch rows ----------------
__global__ __launch_bounds__(256) void exactnn_kernel(
    const float* __restrict__ emb, const float* __restrict__ mem,
    const float* __restrict__ xnorm, const float* __restrict__ ynorm,
    const int* __restrict__ bfrow, unsigned long long* __restrict__ nnbest) {
  __shared__ float feat[NB][DDIM];
  __shared__ float fn[NB];
  for (int e = threadIdx.x; e < NB * DDIM; e += 256) {
    int b = e / DDIM, d = e % DDIM;
    feat[b][d] = emb[(size_t)bfrow[b] * DDIM + d];
  }
  if (threadIdx.x < NB) fn[threadIdx.x] = xnorm[bfrow[threadIdx.x]];
  __syncthreads();
  int wid = threadIdx.x >> 6, lane = threadIdx.x & 63;
  int gw = blockIdx.x * 4 + wid;
  int nw = gridDim.x * 4;
  unsigned long long lb[NB];
#pragma unroll
  for (int b = 0; b < NB; b++) lb[b] = ~0ull;
  for (int m = gw; m < MBANK; m += nw) {
    const float4* mp4 = (const float4*)(mem + (size_t)m * DDIM);
    float acc[NB];
#pragma unroll
    for (int b = 0; b < NB; b++) acc[b] = 0.f;
    for (int d4 = lane; d4 < DDIM / 4; d4 += 64) {
      float4 v = mp4[d4];
#pragma unroll
      for (int b = 0; b < NB; b++) {
        float4 w = *(const float4*)&feat[b][d4 * 4];
        acc[b] = fmaf(v.x, w.x, acc[b]); acc[b] = fmaf(v.y, w.y, acc[b]);
        acc[b] = fmaf(v.z, w.z, acc[b]); acc[b] = fmaf(v.w, w.w, acc[b]);
      }
    }
    float yn = ynorm[m];
#pragma unroll
    for (int b = 0; b < NB; b++) {
      float r = acc[b];
      for (int off = 32; off; off >>= 1) r += __shfl_down(r, off, 64);
      if (lane == 0) {
        float dsq = fmaxf(fn[b] + yn - 2.f * r, 0.f);
        unsigned long long pk =
            ((unsigned long long)__float_as_uint(dsq) << 32) | (unsigned)m;
        if (pk < lb[b]) lb[b] = pk;
      }
    }
  }
  if (lane == 0)
#pragma unroll
    for (int b = 0; b < NB; b++) atomicMin(&nnbest[b], lb[b]);
}

__global__ void extract_bnn_kernel(const unsigned long long* __restrict__ nnbest,
                                   int* __restrict__ bnn) {
  int b = threadIdx.x;
  if (b < NB) bnn[b] = (int)(nnbest[b] & 0xffffffffu);
}

// ---------------- d2: nn_sample vs memory bank ----------------
__global__ __launch_bounds__(256) void d2_kernel(const float* __restrict__ mem,
                                                 const float* __restrict__ ynorm,
                                                 const int* __restrict__ bnn,
                                                 float* __restrict__ d2) {
  __shared__ float nn8[NB][DDIM];
  __shared__ float nnorm[NB];
  for (int e = threadIdx.x; e < NB * DDIM; e += 256) {
    int b = e / DDIM, d = e % DDIM;
    nn8[b][d] = mem[(size_t)bnn[b] * DDIM + d];
  }
  if (threadIdx.x < NB) nnorm[threadIdx.x] = ynorm[bnn[threadIdx.x]];
  __syncthreads();
  int wid = threadIdx.x >> 6, lane = threadIdx.x & 63;
  int gw = blockIdx.x * 4 + wid;
  int nw = gridDim.x * 4;
  for (int m = gw; m < MBANK; m += nw) {
    const float4* mp4 = (const float4*)(mem + (size_t)m * DDIM);
    float acc[NB];
#pragma unroll
    for (int b = 0; b < NB; b++) acc[b] = 0.f;
    for (int d4 = lane; d4 < DDIM / 4; d4 += 64) {
      float4 v = mp4[d4];
#pragma unroll
      for (int b = 0; b < NB; b++) {
        float4 w = *(const float4*)&nn8[b][d4 * 4];
        acc[b] = fmaf(v.x, w.x, acc[b]); acc[b] = fmaf(v.y, w.y, acc[b]);
        acc[b] = fmaf(v.z, w.z, acc[b]); acc[b] = fmaf(v.w, w.w, acc[b]);
      }
    }
    float yn = ynorm[m];
#pragma unroll
    for (int b = 0; b < NB; b++) {
      float r = acc[b];
      for (int off = 32; off; off >>= 1) r += __shfl_down(r, off, 64);
      if (lane == 0) d2[(size_t)b * MBANK + m] = sqrtf(fmaxf(nnorm[b] + yn - 2.f * r, 0.f));
    }
  }
}

// ---------------- top-9 + softmax weight + pred score ----------------
__global__ __launch_bounds__(256) void topk_kernel(
    const float* __restrict__ emb, const float* __restrict__ mem,
    const float* __restrict__ xnorm, const float* __restrict__ ynorm,
    float* __restrict__ d2, const float* __restrict__ bscore,
    const int* __restrict__ bfrow, float* __restrict__ pred) {
  int b = blockIdx.x, t = threadIdx.x;
  __shared__ unsigned long long lred[4];
  __shared__ float fred[4];
  __shared__ int supp[9];
  __shared__ float d3s[9];
  float* row = d2 + (size_t)b * MBANK;
  for (int k = 0; k < 9; k++) {
    unsigned long long bp = ~0ull;
    for (int m = t; m < MBANK; m += 256) {
      unsigned long long pk = ((unsigned long long)__float_as_uint(row[m]) << 32) | (unsigned)m;
      if (pk < bp) bp = pk;
    }
    for (int off = 32; off; off >>= 1) {
      unsigned long long o = __shfl_down(bp, off, 64);
      if (o < bp) bp = o;
    }
    int wid = t >> 6, lane = t & 63;
    if (lane == 0) lred[wid] = bp;
    __syncthreads();
    if (t == 0) {
      for (int w = 1; w < 4; w++) if (lred[w] < lred[0]) lred[0] = lred[w];
      int idx = (int)(lred[0] & 0xffffffffu);
      supp[k] = idx;
      row[idx] = __uint_as_float(0x7f800000u);
    }
    __syncthreads();
  }
  int frow = bfrow[b];
  const float* x = emb + (size_t)frow * DDIM;
  float xnv = xnorm[frow];
  for (int k = 0; k < 9; k++) {
    const float* y = mem + (size_t)supp[k] * DDIM;
    float s = 0.f;
    for (int d = t; d < DDIM; d += 256) s = fmaf(x[d], y[d], s);
    for (int off = 32; off; off >>= 1) s += __shfl_down(s, off, 64);
    if ((t & 63) == 0) fred[t >> 6] = s;
    __syncthreads();
    if (t == 0) {
      float dot = fred[0] + fred[1] + fred[2] + fred[3];
      d3s[k] = sqrtf(fmaxf(xnv - 2.f * dot + ynorm[supp[k]], 0.f));
    }
    __syncthreads();
  }
  if (t == 0) {
    float mx = d3s[0];
    for (int k = 1; k < 9; k++) mx = fmaxf(mx, d3s[k]);
    float sum = 0.f;
    for (int k = 0; k < 9; k++) sum += expf(d3s[k] - mx);
    float w = 1.f - expf(d3s[0] - mx) / sum;
    pred[b] = w * bscore[b];
  }
}

// ---------------- gaussian weights ----------------
__global__ void gauss_kernel(float* __restrict__ g) {
  __shared__ float tmp[KS];
  int t = threadIdx.x;
  if (t < KS) {
    float x = (float)t - (float)(KS - 1) * 0.5f;
    tmp[t] = __expf(-(x * x) / 32.0f);
  }
  __syncthreads();
  if (t == 0) {
    float s = 0.f;
    for (int j = 0; j < KS; j++) s += tmp[j];
    for (int j = 0; j < KS; j++) g[j] = tmp[j] / s;
  }
}

// ---------------- bilinear resize 28 -> 224 ----------------
__global__ __launch_bounds__(256) void resize_kernel(const float* __restrict__ ps,
                                                     float* __restrict__ out) {
  int idx = blockIdx.x * 256 + threadIdx.x;
  if (idx >= NB * HW * HW) return;
  int x = idx % HW, y = (idx / HW) % HW, b = idx / (HW * HW);
  float sx = (x + 0.5f) * 0.125f - 0.5f;
  float sy = (y + 0.5f) * 0.125f - 0.5f;
  int x0 = (int)floorf(sx), y0 = (int)floorf(sy);
  float fx = sx - x0, fy = sy - y0;
  int x0c = min(max(x0, 0), 27), x1c = min(max(x0 + 1, 0), 27);
  int y0c = min(max(y0, 0), 27), y1c = min(max(y0 + 1, 0), 27);
  const float* p = ps + b * PP;
  float v00 = p[y0c * 28 + x0c], v01 = p[y0c * 28 + x1c];
  float v10 = p[y1c * 28 + x0c], v11 = p[y1c * 28 + x1c];
  out[idx] = v00 * (1.f - fy) * (1.f - fx) + v01 * (1.f - fy) * fx +
             v10 * fy * (1.f - fx) + v11 * fy * fx;
}

// ---------------- separable gaussian blur, reflect padding ----------------
__device__ __forceinline__ int reflect224(int i) {
  if (i < 0) i = -i;
  if (i > 223) i = 446 - i;
  return i;
}

__global__ __launch_bounds__(256) void blurv_kernel(const float* __restrict__ in,
                                                    const float* __restrict__ g,
                                                    float* __restrict__ out) {
  __shared__ float gk[KS];
  if (threadIdx.x < KS) gk[threadIdx.x] = g[threadIdx.x];
  __syncthreads();
  int idx = blockIdx.x * 256 + threadIdx.x;
  if (idx >= NB * HW * HW) return;
  int x = idx % HW, y = (idx / HW) % HW, b = idx / (HW * HW);
  const float* base = in + (size_t)b * HW * HW;
  float s = 0.f;
#pragma unroll
  for (int j = 0; j < KS; j++) {
    int yy = reflect224(y - PAD + j);
    s = fmaf(gk[j], base[yy * HW + x], s);
  }
  out[idx] = s;
}

__global__ __launch_bounds__(256) void blurh_kernel(const float* __restrict__ in,
                                                    const float* __restrict__ g,
                                                    float* __restrict__ out) {
  __shared__ float gk[KS];
  if (threadIdx.x < KS) gk[threadIdx.x] = g[threadIdx.x];
  __syncthreads();
  int idx = blockIdx.x * 256 + threadIdx.x;
  if (idx >= NB * HW * HW) return;
  int x = idx % HW, y = (idx / HW) % HW, b = idx / (HW * HW);
  const float* base = in + (size_t)b * HW * HW;
  float s = 0.f;
#pragma unroll
  for (int j = 0; j < KS; j++) {
    int xx = reflect224(x - PAD + j);
    s = fmaf(gk[j], base[y * HW + xx], s);
  }
  out[idx] = s;
}

// ---------------- host ----------------
extern "C" void kernel_launch(void* const* d_in, const int* in_sizes, int n_in,
                              void* d_out, int out_size, void* d_ws, size_t ws_size,
                              hipStream_t stream) {
  const float* emb = (const float*)d_in[0];
  const float* mem = (const float*)d_in[1];
  float* out = (float*)d_out;

  char* ws = (char*)d_ws;
  size_t off = 0;
  auto alloc = [&](size_t bytes) -> void* {
    void* p = ws + off;
    off += (bytes + 255) & ~(size_t)255;
    return p;
  };
  // small allocations first (fallback path uses only these)
  float* ynorm = (float*)alloc(MBANK * 4);
  float* xnorm = (float*)alloc(NROWS * 4);
  unsigned long long* cand = (unsigned long long*)alloc(((size_t)NROWS * CSPLIT + NB) * 8);
  unsigned long long* nnbest = cand + (size_t)NROWS * CSPLIT;
  float* ps = (float*)alloc(NROWS * 4);
  int* loc = (int*)alloc(NROWS * 4);
  float* bscore = (float*)alloc(NB * 4);
  int* bfrow = (int*)alloc(NB * 4);
  int* bnn = (int*)alloc(NB * 4);
  float* d2 = (float*)alloc((size_t)NB * MBANK * 4);
  float* g = (float*)alloc(KS * 4);
  float* rsz = (float*)alloc((size_t)NB * HW * HW * 4);
  float* tmp = (float*)alloc((size_t)NB * HW * HW * 4);
  size_t small_need = off;
  // big bf16 buffers
  unsigned short* emb_h = (unsigned short*)alloc((size_t)NROWS * DDIM * 2);
  unsigned short* mem_h = (unsigned short*)alloc((size_t)NPAD * DDIM * 2);
  size_t full_need = off;

  bool fast = (ws_size >= full_need) && (ws_size >= small_need);

  rownorm_kernel<<<MBANK, 256, 0, stream>>>(mem, ynorm, MBANK);
  rownorm_kernel<<<NROWS, 256, 0, stream>>>(emb, xnorm, NROWS);

  if (fast) {
    convert_kernel<<<4096, 256, 0, stream>>>(mem, mem_h, (long)MBANK * DDIM / 4,
                                             (long)NPAD * DDIM / 4);
    convert_kernel<<<2048, 256, 0, stream>>>(emb, emb_h, (long)NROWS * DDIM / 4,
                                             (long)NROWS * DDIM / 4);
    init_u64_kernel<<<(NROWS * CSPLIT + NB + 255) / 256, 256, 0, stream>>>(
        cand, NROWS * CSPLIT + NB);
    mindist_mfma_kernel<<<dim3(NROWS / 128, CSPLIT), 256, 0, stream>>>(emb_h, mem_h, xnorm,
                                                                       ynorm, cand);
    rerank_kernel<<<NROWS, 256, 0, stream>>>(emb, mem, xnorm, ynorm, cand, ps);
    argmax_kernel<<<NB, 256, 0, stream>>>(ps, (const int*)nullptr, bscore, bfrow, bnn);
    exactnn_kernel<<<400, 256, 0, stream>>>(emb, mem, xnorm, ynorm, bfrow, nnbest);
    extract_bnn_kernel<<<1, NB, 0, stream>>>(nnbest, bnn);
  } else {
    unsigned long long* best = cand;  // alias, NROWS u64 fits
    init_u64_kernel<<<(NROWS + 255) / 256, 256, 0, stream>>>(best, NROWS);
    mindist_kernel<<<dim3(NROWS / BM, CSPLIT), 256, 0, stream>>>(emb, mem, xnorm, ynorm, best);
    unpack_kernel<<<(NROWS + 255) / 256, 256, 0, stream>>>(best, ps, loc);
    argmax_kernel<<<NB, 256, 0, stream>>>(ps, loc, bscore, bfrow, bnn);
  }

  d2_kernel<<<400, 256, 0, stream>>>(mem, ynorm, bnn, d2);
  topk_kernel<<<NB, 256, 0, stream>>>(emb, mem, xnorm, ynorm, d2, bscore, bfrow,
                                      out + (size_t)NB * HW * HW);
  gauss_kernel<<<1, 64, 0, stream>>>(g);
  resize_kernel<<<(NB * HW * HW + 255) / 256, 256, 0, stream>>>(ps, rsz);
  blurv_kernel<<<(NB * HW * HW + 255) / 256, 256, 0, stream>>>(rsz, g, tmp);
  blurh_kernel<<<(NB * HW * HW + 255) / 256, 256, 0, stream>>>(tmp, g, out);
}

// Round 3
// 2209.132 us; speedup vs baseline: 9.4985x; 1.2666x over previous
//
#include <hip/hip_runtime.h>
#include <cstdint>
#include <cstddef>

#define DDIM 1536
#define NROWS 6272      // B*P*P
#define NROWPAD 6400    // 25*256
#define MBANK 50000
#define NCOLPAD 50176   // 196*256
#define NRT 25
#define NCT 196
#define NKT 24          // 1536 / 64
#define NB 8
#define PP 784
#define HW 224
#define KS 33
#define PAD 16

typedef __attribute__((ext_vector_type(8))) short short8v;
typedef __attribute__((ext_vector_type(4))) float floatx4;

__device__ __forceinline__ unsigned long long u64min(unsigned long long a, unsigned long long b) {
  return a < b ? a : b;
}

// ---------------- fp32 -> bf16 (RNE) ----------------
__device__ __forceinline__ unsigned short f2bf(float f) {
  unsigned u = __float_as_uint(f);
  return (unsigned short)((u + 0x7fffu + ((u >> 16) & 1u)) >> 16);
}

// ---------------- fused convert + row norm (zero-pads tail rows) ----------------
__global__ __launch_bounds__(256) void convnorm_kernel(const float* __restrict__ in,
                                                       unsigned short* __restrict__ out,
                                                       float* __restrict__ norm,
                                                       int valid_rows) {
  int row = blockIdx.x;
  int t = threadIdx.x;
  float s = 0.f;
  ushort4* dst = (ushort4*)(out + (size_t)row * DDIM);
  if (row < valid_rows) {
    const float4* src = (const float4*)(in + (size_t)row * DDIM);
    for (int d = t; d < DDIM / 4; d += 256) {
      float4 v = src[d];
      s = fmaf(v.x, v.x, s); s = fmaf(v.y, v.y, s);
      s = fmaf(v.z, v.z, s); s = fmaf(v.w, v.w, s);
      ushort4 o;
      o.x = f2bf(v.x); o.y = f2bf(v.y); o.z = f2bf(v.z); o.w = f2bf(v.w);
      dst[d] = o;
    }
  } else {
    ushort4 z; z.x = z.y = z.z = z.w = 0;
    for (int d = t; d < DDIM / 4; d += 256) dst[d] = z;
  }
  for (int off = 32; off; off >>= 1) s += __shfl_down(s, off, 64);
  __shared__ float ls[4];
  int wave = t >> 6, lane = t & 63;
  if (lane == 0) ls[wave] = s;
  __syncthreads();
  if (t == 0) norm[row] = ls[0] + ls[1] + ls[2] + ls[3];
}

// ---------------- plain rownorm (fallback path) ----------------
__global__ __launch_bounds__(256) void rownorm_kernel(const float* __restrict__ x,
                                                      float* __restrict__ out, int rows) {
  int row = blockIdx.x;
  if (row >= rows) return;
  const float4* p4 = (const float4*)(x + (size_t)row * DDIM);
  float s = 0.f;
  for (int d = threadIdx.x; d < DDIM / 4; d += 256) {
    float4 v = p4[d];
    s = fmaf(v.x, v.x, s); s = fmaf(v.y, v.y, s);
    s = fmaf(v.z, v.z, s); s = fmaf(v.w, v.w, s);
  }
  for (int off = 32; off; off >>= 1) s += __shfl_down(s, off, 64);
  __shared__ float ls[4];
  int wid = threadIdx.x >> 6, lane = threadIdx.x & 63;
  if (lane == 0) ls[wid] = s;
  __syncthreads();
  if (threadIdx.x == 0) out[row] = ls[0] + ls[1] + ls[2] + ls[3];
}

__global__ void init_u64_kernel(unsigned long long* p, int n) {
  int i = blockIdx.x * 256 + threadIdx.x;
  if (i < n) p[i] = ~0ull;
}

// ============== 256x256 / BK=64 / 8-wave counted-vmcnt MFMA min-dist ==============
__global__ __launch_bounds__(512) void mindist_mfma_kernel(
    const unsigned short* __restrict__ Ah, const unsigned short* __restrict__ Bh,
    const float* __restrict__ xnorm, const float* __restrict__ ynorm,
    unsigned long long* __restrict__ cand) {
  __shared__ char smem[131072];  // A: [0,65536) = 2 bufs x 32KB ; B: [65536,131072)

  const int t = threadIdx.x;
  const int lane = t & 63, wid = t >> 6;
  const int wm = wid >> 2, wn = wid & 3;
  const int l15 = lane & 15, g = lane >> 4;

  // bijective XCD swizzle (nwg = 4900; q=612, r=4)
  const int nwg = NRT * NCT;
  const int q8 = nwg >> 3, r8 = nwg & 7;
  int orig = blockIdx.x;
  int xcd = orig & 7, pos = orig >> 3;
  int wg = (xcd < r8 ? xcd * (q8 + 1) : r8 * (q8 + 1) + (xcd - r8) * q8) + pos;
  const int rt = wg / NCT, ct = wg % NCT;
  const int row0 = rt * 256;
  const int c0 = ct * 256;

  // fragment read address pieces (swizzle: phys_chunk = logical_chunk ^ (row&7);
  // row&7 == l15&7 since all other row terms are multiples of 8/16)
  const int aBase = wm * 16384 + l15 * 128;
  const int bBase = 65536 + (wn * 64 + l15) * 128;
  int cks[2];
  cks[0] = ((0 + g) ^ (l15 & 7)) * 16;
  cks[1] = ((4 + g) ^ (l15 & 7)) * 16;

  // stage source bases: thread covers flat 16B chunk f = i*512 + t of the 256x64 tile
  // r = f>>3 = i*64 + (t>>3);  phys chunk j = t&7;  logical chunk = j ^ (r&7) = (t&7)^((t>>3)&7)
  const int cc = (t & 7) ^ ((t >> 3) & 7);
  const unsigned short* pa0 = Ah + (size_t)(row0 + (t >> 3)) * DDIM + cc * 8;
  const unsigned short* pb0 = Bh + (size_t)(c0 + (t >> 3)) * DDIM + cc * 8;

#define STAGEAB(kt, d)                                                                   \
  {                                                                                      \
    _Pragma("unroll") for (int i = 0; i < 4; i++) {                                      \
      __builtin_amdgcn_global_load_lds(                                                  \
          (const __attribute__((address_space(1))) void*)(pa0 + (size_t)i * (64 * DDIM) +\
                                                          (kt) * 64),                    \
          (__attribute__((address_space(3))) void*)(smem + (d) * 32768 + i * 8192 +      \
                                                    wid * 1024),                         \
          16, 0, 0);                                                                     \
    }                                                                                    \
    _Pragma("unroll") for (int i = 0; i < 4; i++) {                                      \
      __builtin_amdgcn_global_load_lds(                                                  \
          (const __attribute__((address_space(1))) void*)(pb0 + (size_t)i * (64 * DDIM) +\
                                                          (kt) * 64),                    \
          (__attribute__((address_space(3))) void*)(smem + 65536 + (d) * 32768 +         \
                                                    i * 8192 + wid * 1024),              \
          16, 0, 0);                                                                     \
    }                                                                                    \
  }

  floatx4 acc[2][4][4];
  floatx4 zz = {0.f, 0.f, 0.f, 0.f};
#pragma unroll
  for (int qm = 0; qm < 2; qm++)
#pragma unroll
    for (int mf = 0; mf < 4; mf++)
#pragma unroll
      for (int nf = 0; nf < 4; nf++) acc[qm][mf][nf] = zz;

  // prologue: stage K-tiles 0 and 1
  STAGEAB(0, 0);
  STAGEAB(1, 1);

  for (int kt = 0; kt < NKT; ++kt) {
    const int d = kt & 1;
    // gate: own loads for this K-tile landed (8 younger = next tile's loads)
    if (kt < NKT - 1) {
      asm volatile("s_waitcnt vmcnt(8)" ::: "memory");
    } else {
      asm volatile("s_waitcnt vmcnt(0)" ::: "memory");
    }
    __builtin_amdgcn_sched_barrier(0);
    __builtin_amdgcn_s_barrier();  // all waves' loads landed -> LDS tile complete
    __builtin_amdgcn_sched_barrier(0);
    const int dOff = d * 32768;
#pragma unroll
    for (int qm = 0; qm < 2; qm++) {
      short8v ra[4][2], rb[4][2];
#pragma unroll
      for (int mf = 0; mf < 4; mf++) {
#pragma unroll
        for (int ks = 0; ks < 2; ks++) {
          ra[mf][ks] = *(const short8v*)(smem + dOff + aBase +
                                         (qm * 64 + mf * 16) * 128 + cks[ks]);
          rb[mf][ks] = *(const short8v*)(smem + dOff + bBase + mf * 16 * 128 + cks[ks]);
        }
      }
      asm volatile("s_waitcnt lgkmcnt(0)" ::: "memory");
      __builtin_amdgcn_sched_barrier(0);
      __builtin_amdgcn_s_setprio(1);
#pragma unroll
      for (int mf = 0; mf < 4; mf++)
#pragma unroll
        for (int nf = 0; nf < 4; nf++)
#pragma unroll
          for (int ks = 0; ks < 2; ks++)
            acc[qm][mf][nf] = __builtin_amdgcn_mfma_f32_16x16x32_bf16(
                ra[mf][ks], rb[nf][ks], acc[qm][mf][nf], 0, 0, 0);
      __builtin_amdgcn_s_setprio(0);
    }
    __builtin_amdgcn_sched_barrier(0);
    __builtin_amdgcn_s_barrier();  // all waves done reading buf d
    __builtin_amdgcn_sched_barrier(0);
    if (kt < NKT - 2) STAGEAB(kt + 2, d);  // restage just-freed buffer
  }
#undef STAGEAB

  // epilogue: fold acc -> per-row packed min -> cand[row][ct]
  float yn[4];
  int colv[4];
#pragma unroll
  for (int nf = 0; nf < 4; nf++) {
    int col = c0 + wn * 64 + nf * 16 + l15;
    colv[nf] = col;
    yn[nf] = (col < MBANK) ? ynorm[col] : 0.f;
  }
#pragma unroll
  for (int qm = 0; qm < 2; qm++) {
#pragma unroll
    for (int mf = 0; mf < 4; mf++) {
      int rowb = row0 + wm * 128 + qm * 64 + mf * 16 + g * 4;
#pragma unroll
      for (int q = 0; q < 4; q++) {
        float xnq = xnorm[rowb + q];
        unsigned long long best = ~0ull;
#pragma unroll
        for (int nf = 0; nf < 4; nf++) {
          if (colv[nf] < MBANK) {
            float dsq = fmaxf(xnq + yn[nf] - 2.f * acc[qm][mf][nf][q], 0.f);
            unsigned long long p =
                ((unsigned long long)__float_as_uint(dsq) << 32) | (unsigned)colv[nf];
            best = u64min(best, p);
          }
        }
#pragma unroll
        for (int mask = 1; mask <= 8; mask <<= 1)
          best = u64min(best, __shfl_xor(best, mask, 64));
        if (l15 == 0 && rowb + q < NROWS)
          atomicMin(&cand[(size_t)(rowb + q) * NCT + ct], best);
      }
    }
  }
}

// ---------------- gated fp32 re-rank of the 196 per-slot winners ----------------
__global__ __launch_bounds__(256) void rerank_kernel(
    const float* __restrict__ emb, const float* __restrict__ mem,
    const float* __restrict__ xnorm, const float* __restrict__ ynorm,
    const unsigned long long* __restrict__ cand, float* __restrict__ ps) {
  int row = blockIdx.x, t = threadIdx.x;
  int lane = t & 63, wave = t >> 6;
  __shared__ unsigned long long lred[4];
  __shared__ int glist[NCT];
  __shared__ int gcount;
  __shared__ float gmin;
  const unsigned long long* crow = cand + (size_t)row * NCT;
  unsigned long long mn = ~0ull;
  for (int i = t; i < NCT; i += 256) mn = u64min(mn, crow[i]);
  for (int off = 32; off; off >>= 1) {
    unsigned long long o = __shfl_down(mn, off, 64);
    mn = u64min(mn, o);
  }
  if (lane == 0) lred[wave] = mn;
  if (t == 0) gcount = 0;
  __syncthreads();
  if (t == 0) {
    unsigned long long m0 = lred[0];
    for (int w = 1; w < 4; w++) m0 = u64min(m0, lred[w]);
    gmin = __uint_as_float((unsigned)(m0 >> 32));
  }
  __syncthreads();
  float gate = gmin + 6.0f;  // >> 14 sigma of bf16 dot error
  if (t < NCT) {
    unsigned long long v = crow[t];
    float dq = __uint_as_float((unsigned)(v >> 32));
    if (dq <= gate) {
      int idx = atomicAdd(&gcount, 1);
      glist[idx] = (int)(v & 0xffffffffu);
    }
  }
  __syncthreads();
  int ng = gcount;
  float xnv = xnorm[row];
  const float4* xp = (const float4*)(emb + (size_t)row * DDIM);
  unsigned long long best = ~0ull;
  for (int gi = wave; gi < ng; gi += 4) {
    int col = glist[gi];
    const float4* yp = (const float4*)(mem + (size_t)col * DDIM);
    float s = 0.f;
    for (int d4 = lane; d4 < DDIM / 4; d4 += 64) {
      float4 a = xp[d4], b = yp[d4];
      s = fmaf(a.x, b.x, s); s = fmaf(a.y, b.y, s);
      s = fmaf(a.z, b.z, s); s = fmaf(a.w, b.w, s);
    }
    for (int off = 32; off; off >>= 1) s += __shfl_down(s, off, 64);
    if (lane == 0) {
      float dsq = fmaxf(xnv + ynorm[col] - 2.f * s, 0.f);
      unsigned long long p =
          ((unsigned long long)__float_as_uint(dsq) << 32) | (unsigned)col;
      best = u64min(best, p);
    }
  }
  if (lane == 0) lred[wave] = best;
  __syncthreads();
  if (t == 0) {
    unsigned long long b = lred[0];
    for (int w = 1; w < 4; w++) b = u64min(b, lred[w]);
    ps[row] = sqrtf(__uint_as_float((unsigned)(b >> 32)));
  }
}

// ============== fallback fp32 min-distance GEMM (ws too small) ==============
#define BM 128
#define BN 128
#define DKC 16
#define FCSPLIT 16
#define FCT ((MBANK + BN - 1) / BN)
#define FCPB ((FCT + FCSPLIT - 1) / FCSPLIT)

__global__ __launch_bounds__(256) void mindist_kernel(
    const float* __restrict__ A, const float* __restrict__ Bm,
    const float* __restrict__ xnorm, const float* __restrict__ ynorm,
    unsigned long long* __restrict__ best) {
  __shared__ float Asf[DKC][BM];
  __shared__ float Bsf[DKC][BN];
  int t = threadIdx.x;
  int tx = t & 15, ty = t >> 4;
  int row0 = blockIdx.x * BM;
  int rloc[8], cloc[8];
#pragma unroll
  for (int i = 0; i < 4; i++) {
    rloc[i] = ty * 4 + i; rloc[i + 4] = 64 + ty * 4 + i;
    cloc[i] = tx * 4 + i; cloc[i + 4] = 64 + tx * 4 + i;
  }
  float xnv[8];
#pragma unroll
  for (int i = 0; i < 8; i++) xnv[i] = xnorm[row0 + rloc[i]];
  unsigned long long bestr[8];
#pragma unroll
  for (int i = 0; i < 8; i++) bestr[i] = ~0ull;
  int ct_begin = blockIdx.y * FCPB;
  int ct_end = ct_begin + FCPB; if (ct_end > FCT) ct_end = FCT;
  for (int ct = ct_begin; ct < ct_end; ++ct) {
    int c0 = ct * BN;
    float acc[8][8];
#pragma unroll
    for (int i = 0; i < 8; i++)
#pragma unroll
      for (int j = 0; j < 8; j++) acc[i][j] = 0.f;
    for (int dk = 0; dk < DDIM; dk += DKC) {
#pragma unroll
      for (int s = 0; s < 2; ++s) {
        int q = t + s * 256;
        int r = q >> 2, c4 = q & 3;
        float4 va = *(const float4*)(A + (size_t)(row0 + r) * DDIM + dk + c4 * 4);
        Asf[c4 * 4 + 0][r] = va.x; Asf[c4 * 4 + 1][r] = va.y;
        Asf[c4 * 4 + 2][r] = va.z; Asf[c4 * 4 + 3][r] = va.w;
        int col = c0 + r;
        float4 vb = make_float4(0.f, 0.f, 0.f, 0.f);
        if (col < MBANK) vb = *(const float4*)(Bm + (size_t)col * DDIM + dk + c4 * 4);
        Bsf[c4 * 4 + 0][r] = vb.x; Bsf[c4 * 4 + 1][r] = vb.y;
        Bsf[c4 * 4 + 2][r] = vb.z; Bsf[c4 * 4 + 3][r] = vb.w;
      }
      __syncthreads();
#pragma unroll
      for (int k = 0; k < DKC; k++) {
        float4 a0 = *(const float4*)&Asf[k][ty * 4];
        float4 a1 = *(const float4*)&Asf[k][64 + ty * 4];
        float4 b0 = *(const float4*)&Bsf[k][tx * 4];
        float4 b1 = *(const float4*)&Bsf[k][64 + tx * 4];
        float av[8] = {a0.x, a0.y, a0.z, a0.w, a1.x, a1.y, a1.z, a1.w};
        float bv[8] = {b0.x, b0.y, b0.z, b0.w, b1.x, b1.y, b1.z, b1.w};
#pragma unroll
        for (int i = 0; i < 8; i++)
#pragma unroll
          for (int j = 0; j < 8; j++) acc[i][j] = fmaf(av[i], bv[j], acc[i][j]);
      }
      __syncthreads();
    }
#pragma unroll
    for (int j = 0; j < 8; j++) {
      int col = c0 + cloc[j];
      if (col < MBANK) {
        float yn = ynorm[col];
#pragma unroll
        for (int i = 0; i < 8; i++) {
          float dsq = fmaxf(xnv[i] + yn - 2.f * acc[i][j], 0.f);
          unsigned long long pk =
              ((unsigned long long)__float_as_uint(dsq) << 32) | (unsigned)col;
          if (pk < bestr[i]) bestr[i] = pk;
        }
      }
    }
  }
#pragma unroll
  for (int i = 0; i < 8; i++) atomicMin(&best[row0 + rloc[i]], bestr[i]);
}

__global__ void unpack_kernel(const unsigned long long* __restrict__ best,
                              float* __restrict__ ps, int* __restrict__ loc) {
  int i = blockIdx.x * 256 + threadIdx.x;
  if (i >= NROWS) return;
  unsigned long long v = best[i];
  ps[i] = sqrtf(__uint_as_float((unsigned)(v >> 32)));
  loc[i] = (int)(v & 0xffffffffu);
}

// ---------------- per-batch argmax (loc optional) ----------------
__global__ __launch_bounds__(256) void argmax_kernel(const float* __restrict__ ps,
                                                     const int* __restrict__ loc,
                                                     float* __restrict__ bscore,
                                                     int* __restrict__ bfrow,
                                                     int* __restrict__ bnn) {
  int b = blockIdx.x, t = threadIdx.x;
  unsigned long long bp = 0;
  for (int p = t; p < PP; p += 256) {
    unsigned long long pk = ((unsigned long long)__float_as_uint(ps[b * PP + p]) << 32) |
                            (unsigned)(0xffffffffu - (unsigned)p);
    if (pk > bp) bp = pk;
  }
  for (int off = 32; off; off >>= 1) {
    unsigned long long o = __shfl_down(bp, off, 64);
    if (o > bp) bp = o;
  }
  __shared__ unsigned long long ls[4];
  int wid = t >> 6, lane = t & 63;
  if (lane == 0) ls[wid] = bp;
  __syncthreads();
  if (t == 0) {
    for (int w = 1; w < 4; w++) if (ls[w] > ls[0]) ls[0] = ls[w];
    unsigned p = 0xffffffffu - (unsigned)(ls[0] & 0xffffffffu);
    bscore[b] = __uint_as_float((unsigned)(ls[0] >> 32));
    bfrow[b] = b * PP + (int)p;
    if (loc) bnn[b] = loc[b * PP + (int)p];
  }
}

// ---------------- exact fp32 argmin over bank for the 8 max-patch rows ----------------
__global__ __launch_bounds__(256) void exactnn_kernel(
    const float* __restrict__ emb, const float* __restrict__ mem,
    const float* __restrict__ xnorm, const float* __restrict__ ynorm,
    const int* __restrict__ bfrow, unsigned long long* __restrict__ nnbest) {
  __shared__ float feat[NB][DDIM];
  __shared__ float fn[NB];
  for (int e = threadIdx.x; e < NB * DDIM; e += 256) {
    int b = e / DDIM, d = e % DDIM;
    feat[b][d] = emb[(size_t)bfrow[b] * DDIM + d];
  }
  if (threadIdx.x < NB) fn[threadIdx.x] = xnorm[bfrow[threadIdx.x]];
  __syncthreads();
  int wid = threadIdx.x >> 6, lane = threadIdx.x & 63;
  int gw = blockIdx.x * 4 + wid;
  int nw = gridDim.x * 4;
  unsigned long long lb[NB];
#pragma unroll
  for (int b = 0; b < NB; b++) lb[b] = ~0ull;
  for (int m = gw; m < MBANK; m += nw) {
    const float4* mp4 = (const float4*)(mem + (size_t)m * DDIM);
    float acc[NB];
#pragma unroll
    for (int b = 0; b < NB; b++) acc[b] = 0.f;
    for (int d4 = lane; d4 < DDIM / 4; d4 += 64) {
      float4 v = mp4[d4];
#pragma unroll
      for (int b = 0; b < NB; b++) {
        float4 w = *(const float4*)&feat[b][d4 * 4];
        acc[b] = fmaf(v.x, w.x, acc[b]); acc[b] = fmaf(v.y, w.y, acc[b]);
        acc[b] = fmaf(v.z, w.z, acc[b]); acc[b] = fmaf(v.w, w.w, acc[b]);
      }
    }
    float yn = ynorm[m];
#pragma unroll
    for (int b = 0; b < NB; b++) {
      float r = acc[b];
      for (int off = 32; off; off >>= 1) r += __shfl_down(r, off, 64);
      if (lane == 0) {
        float dsq = fmaxf(fn[b] + yn - 2.f * r, 0.f);
        unsigned long long pk =
            ((unsigned long long)__float_as_uint(dsq) << 32) | (unsigned)m;
        if (pk < lb[b]) lb[b] = pk;
      }
    }
  }
  if (lane == 0)
#pragma unroll
    for (int b = 0; b < NB; b++) atomicMin(&nnbest[b], lb[b]);
}

__global__ void extract_bnn_kernel(const unsigned long long* __restrict__ nnbest,
                                   int* __restrict__ bnn) {
  int b = threadIdx.x;
  if (b < NB) bnn[b] = (int)(nnbest[b] & 0xffffffffu);
}

// ---------------- d2: nn_sample vs memory bank ----------------
__global__ __launch_bounds__(256) void d2_kernel(const float* __restrict__ mem,
                                                 const float* __restrict__ ynorm,
                                                 const int* __restrict__ bnn,
                                                 float* __restrict__ d2) {
  __shared__ float nn8[NB][DDIM];
  __shared__ float nnorm[NB];
  for (int e = threadIdx.x; e < NB * DDIM; e += 256) {
    int b = e / DDIM, d = e % DDIM;
    nn8[b][d] = mem[(size_t)bnn[b] * DDIM + d];
  }
  if (threadIdx.x < NB) nnorm[threadIdx.x] = ynorm[bnn[threadIdx.x]];
  __syncthreads();
  int wid = threadIdx.x >> 6, lane = threadIdx.x & 63;
  int gw = blockIdx.x * 4 + wid;
  int nw = gridDim.x * 4;
  for (int m = gw; m < MBANK; m += nw) {
    const float4* mp4 = (const float4*)(mem + (size_t)m * DDIM);
    float acc[NB];
#pragma unroll
    for (int b = 0; b < NB; b++) acc[b] = 0.f;
    for (int d4 = lane; d4 < DDIM / 4; d4 += 64) {
      float4 v = mp4[d4];
#pragma unroll
      for (int b = 0; b < NB; b++) {
        float4 w = *(const float4*)&nn8[b][d4 * 4];
        acc[b] = fmaf(v.x, w.x, acc[b]); acc[b] = fmaf(v.y, w.y, acc[b]);
        acc[b] = fmaf(v.z, w.z, acc[b]); acc[b] = fmaf(v.w, w.w, acc[b]);
      }
    }
    float yn = ynorm[m];
#pragma unroll
    for (int b = 0; b < NB; b++) {
      float r = acc[b];
      for (int off = 32; off; off >>= 1) r += __shfl_down(r, off, 64);
      if (lane == 0) d2[(size_t)b * MBANK + m] = sqrtf(fmaxf(nnorm[b] + yn - 2.f * r, 0.f));
    }
  }
}

// ---------------- top-9 + softmax weight + pred score ----------------
__global__ __launch_bounds__(256) void topk_kernel(
    const float* __restrict__ emb, const float* __restrict__ mem,
    const float* __restrict__ xnorm, const float* __restrict__ ynorm,
    float* __restrict__ d2, const float* __restrict__ bscore,
    const int* __restrict__ bfrow, float* __restrict__ pred) {
  int b = blockIdx.x, t = threadIdx.x;
  __shared__ unsigned long long lred[4];
  __shared__ float fred[4];
  __shared__ int supp[9];
  __shared__ float d3s[9];
  float* row = d2 + (size_t)b * MBANK;
  for (int k = 0; k < 9; k++) {
    unsigned long long bp = ~0ull;
    for (int m = t; m < MBANK; m += 256) {
      unsigned long long pk = ((unsigned long long)__float_as_uint(row[m]) << 32) | (unsigned)m;
      if (pk < bp) bp = pk;
    }
    for (int off = 32; off; off >>= 1) {
      unsigned long long o = __shfl_down(bp, off, 64);
      if (o < bp) bp = o;
    }
    int wid = t >> 6, lane = t & 63;
    if (lane == 0) lred[wid] = bp;
    __syncthreads();
    if (t == 0) {
      for (int w = 1; w < 4; w++) if (lred[w] < lred[0]) lred[0] = lred[w];
      int idx = (int)(lred[0] & 0xffffffffu);
      supp[k] = idx;
      row[idx] = __uint_as_float(0x7f800000u);
    }
    __syncthreads();
  }
  int frow = bfrow[b];
  const float* x = emb + (size_t)frow * DDIM;
  float xnv = xnorm[frow];
  for (int k = 0; k < 9; k++) {
    const float* y = mem + (size_t)supp[k] * DDIM;
    float s = 0.f;
    for (int d = t; d < DDIM; d += 256) s = fmaf(x[d], y[d], s);
    for (int off = 32; off; off >>= 1) s += __shfl_down(s, off, 64);
    if ((t & 63) == 0) fred[t >> 6] = s;
    __syncthreads();
    if (t == 0) {
      float dot = fred[0] + fred[1] + fred[2] + fred[3];
      d3s[k] = sqrtf(fmaxf(xnv - 2.f * dot + ynorm[supp[k]], 0.f));
    }
    __syncthreads();
  }
  if (t == 0) {
    float mx = d3s[0];
    for (int k = 1; k < 9; k++) mx = fmaxf(mx, d3s[k]);
    float sum = 0.f;
    for (int k = 0; k < 9; k++) sum += expf(d3s[k] - mx);
    float w = 1.f - expf(d3s[0] - mx) / sum;
    pred[b] = w * bscore[b];
  }
}

// ---------------- gaussian weights ----------------
__global__ void gauss_kernel(float* __restrict__ g) {
  __shared__ float tmp[KS];
  int t = threadIdx.x;
  if (t < KS) {
    float x = (float)t - (float)(KS - 1) * 0.5f;
    tmp[t] = __expf(-(x * x) / 32.0f);
  }
  __syncthreads();
  if (t == 0) {
    float s = 0.f;
    for (int j = 0; j < KS; j++) s += tmp[j];
    for (int j = 0; j < KS; j++) g[j] = tmp[j] / s;
  }
}

// ---------------- bilinear resize 28 -> 224 ----------------
__global__ __launch_bounds__(256) void resize_kernel(const float* __restrict__ ps,
                                                     float* __restrict__ out) {
  int idx = blockIdx.x * 256 + threadIdx.x;
  if (idx >= NB * HW * HW) return;
  int x = idx % HW, y = (idx / HW) % HW, b = idx / (HW * HW);
  float sx = (x + 0.5f) * 0.125f - 0.5f;
  float sy = (y + 0.5f) * 0.125f - 0.5f;
  int x0 = (int)floorf(sx), y0 = (int)floorf(sy);
  float fx = sx - x0, fy = sy - y0;
  int x0c = min(max(x0, 0), 27), x1c = min(max(x0 + 1, 0), 27);
  int y0c = min(max(y0, 0), 27), y1c = min(max(y0 + 1, 0), 27);
  const float* p = ps + b * PP;
  float v00 = p[y0c * 28 + x0c], v01 = p[y0c * 28 + x1c];
  float v10 = p[y1c * 28 + x0c], v11 = p[y1c * 28 + x1c];
  out[idx] = v00 * (1.f - fy) * (1.f - fx) + v01 * (1.f - fy) * fx +
             v10 * fy * (1.f - fx) + v11 * fy * fx;
}

// ---------------- separable gaussian blur, reflect padding ----------------
__device__ __forceinline__ int reflect224(int i) {
  if (i < 0) i = -i;
  if (i > 223) i = 446 - i;
  return i;
}

__global__ __launch_bounds__(256) void blurv_kernel(const float* __restrict__ in,
                                                    const float* __restrict__ g,
                                                    float* __restrict__ out) {
  __shared__ float gk[KS];
  if (threadIdx.x < KS) gk[threadIdx.x] = g[threadIdx.x];
  __syncthreads();
  int idx = blockIdx.x * 256 + threadIdx.x;
  if (idx >= NB * HW * HW) return;
  int x = idx % HW, y = (idx / HW) % HW, b = idx / (HW * HW);
  const float* base = in + (size_t)b * HW * HW;
  float s = 0.f;
#pragma unroll
  for (int j = 0; j < KS; j++) {
    int yy = reflect224(y - PAD + j);
    s = fmaf(gk[j], base[yy * HW + x], s);
  }
  out[idx] = s;
}

__global__ __launch_bounds__(256) void blurh_kernel(const float* __restrict__ in,
                                                    const float* __restrict__ g,
                                                    float* __restrict__ out) {
  __shared__ float gk[KS];
  if (threadIdx.x < KS) gk[threadIdx.x] = g[threadIdx.x];
  __syncthreads();
  int idx = blockIdx.x * 256 + threadIdx.x;
  if (idx >= NB * HW * HW) return;
  int x = idx % HW, y = (idx / HW) % HW, b = idx / (HW * HW);
  const float* base = in + (size_t)b * HW * HW;
  float s = 0.f;
#pragma unroll
  for (int j = 0; j < KS; j++) {
    int xx = reflect224(x - PAD + j);
    s = fmaf(gk[j], base[y * HW + xx], s);
  }
  out[idx] = s;
}

// ---------------- host ----------------
extern "C" void kernel_launch(void* const* d_in, const int* in_sizes, int n_in,
                              void* d_out, int out_size, void* d_ws, size_t ws_size,
                              hipStream_t stream) {
  const float* emb = (const float*)d_in[0];
  const float* mem = (const float*)d_in[1];
  float* out = (float*)d_out;

  char* ws = (char*)d_ws;
  size_t off = 0;
  auto alloc = [&](size_t bytes) -> void* {
    void* p = ws + off;
    off += (bytes + 255) & ~(size_t)255;
    return p;
  };
  // small allocations first (fallback path uses only these)
  float* ynorm = (float*)alloc((size_t)NCOLPAD * 4);
  float* xnorm = (float*)alloc((size_t)NROWPAD * 4);
  unsigned long long* cand =
      (unsigned long long*)alloc(((size_t)NROWS * NCT + NB) * 8);
  unsigned long long* nnbest = cand + (size_t)NROWS * NCT;
  float* ps = (float*)alloc(NROWS * 4);
  int* loc = (int*)alloc(NROWS * 4);
  float* bscore = (float*)alloc(NB * 4);
  int* bfrow = (int*)alloc(NB * 4);
  int* bnn = (int*)alloc(NB * 4);
  float* d2 = (float*)alloc((size_t)NB * MBANK * 4);
  float* g = (float*)alloc(KS * 4);
  float* rsz = (float*)alloc((size_t)NB * HW * HW * 4);
  float* tmp = (float*)alloc((size_t)NB * HW * HW * 4);
  // big bf16 buffers
  unsigned short* emb_h = (unsigned short*)alloc((size_t)NROWPAD * DDIM * 2);
  unsigned short* mem_h = (unsigned short*)alloc((size_t)NCOLPAD * DDIM * 2);
  size_t full_need = off;

  bool fast = (ws_size >= full_need);

  if (fast) {
    convnorm_kernel<<<NCOLPAD, 256, 0, stream>>>(mem, mem_h, ynorm, MBANK);
    convnorm_kernel<<<NROWPAD, 256, 0, stream>>>(emb, emb_h, xnorm, NROWS);
    init_u64_kernel<<<(NROWS * NCT + NB + 255) / 256, 256, 0, stream>>>(
        cand, NROWS * NCT + NB);
    mindist_mfma_kernel<<<NRT * NCT, 512, 0, stream>>>(emb_h, mem_h, xnorm, ynorm, cand);
    rerank_kernel<<<NROWS, 256, 0, stream>>>(emb, mem, xnorm, ynorm, cand, ps);
    argmax_kernel<<<NB, 256, 0, stream>>>(ps, (const int*)nullptr, bscore, bfrow, bnn);
    exactnn_kernel<<<400, 256, 0, stream>>>(emb, mem, xnorm, ynorm, bfrow, nnbest);
    extract_bnn_kernel<<<1, NB, 0, stream>>>(nnbest, bnn);
  } else {
    rownorm_kernel<<<MBANK, 256, 0, stream>>>(mem, ynorm, MBANK);
    rownorm_kernel<<<NROWS, 256, 0, stream>>>(emb, xnorm, NROWS);
    unsigned long long* best = cand;  // alias
    init_u64_kernel<<<(NROWS + 255) / 256, 256, 0, stream>>>(best, NROWS);
    mindist_kernel<<<dim3(NROWS / BM, FCSPLIT), 256, 0, stream>>>(emb, mem, xnorm, ynorm,
                                                                  best);
    unpack_kernel<<<(NROWS + 255) / 256, 256, 0, stream>>>(best, ps, loc);
    argmax_kernel<<<NB, 256, 0, stream>>>(ps, loc, bscore, bfrow, bnn);
  }

  d2_kernel<<<400, 256, 0, stream>>>(mem, ynorm, bnn, d2);
  topk_kernel<<<NB, 256, 0, stream>>>(emb, mem, xnorm, ynorm, d2, bscore, bfrow,
                                      out + (size_t)NB * HW * HW);
  gauss_kernel<<<1, 64, 0, stream>>>(g);
  resize_kernel<<<(NB * HW * HW + 255) / 256, 256, 0, stream>>>(ps, rsz);
  blurv_kernel<<<(NB * HW * HW + 255) / 256, 256, 0, stream>>>(rsz, g, tmp);
  blurh_kernel<<<(NB * HW * HW + 255) / 256, 256, 0, stream>>>(tmp, g, out);
}

// Round 4
// 1712.431 us; speedup vs baseline: 12.2536x; 1.2901x over previous
//
#include <hip/hip_runtime.h>
#include <cstdint>
#include <cstddef>

#define DDIM 1536
#define NROWS 6272      // B*P*P
#define NROWPAD 6400    // 25*256
#define MBANK 50000
#define NCOLPAD 50176   // 196*256
#define NRT 25
#define NCT 196
#define NKT 24          // 1536 / 64
#define NB 8
#define PP 784
#define HW 224
#define KS 33
#define PAD 16

typedef __attribute__((ext_vector_type(8))) short short8v;
typedef __attribute__((ext_vector_type(4))) float floatx4;

__device__ __forceinline__ unsigned long long u64min(unsigned long long a, unsigned long long b) {
  return a < b ? a : b;
}

// ---------------- fp32 -> bf16 (RNE) ----------------
__device__ __forceinline__ unsigned short f2bf(float f) {
  unsigned u = __float_as_uint(f);
  return (unsigned short)((u + 0x7fffu + ((u >> 16) & 1u)) >> 16);
}

// ---------------- fused convert + row norm, wave-per-row (no syncs) ----------------
__global__ __launch_bounds__(256) void convnorm_kernel(const float* __restrict__ in,
                                                       unsigned short* __restrict__ out,
                                                       float* __restrict__ norm,
                                                       int valid_rows, int total_rows) {
  int row = blockIdx.x * 4 + (threadIdx.x >> 6);
  int lane = threadIdx.x & 63;
  if (row >= total_rows) return;
  ushort4* dst = (ushort4*)(out + (size_t)row * DDIM);
  float s = 0.f;
  if (row < valid_rows) {
    const float4* src = (const float4*)(in + (size_t)row * DDIM);
#pragma unroll
    for (int i = 0; i < 6; i++) {
      int d = lane + i * 64;
      float4 v = src[d];
      s = fmaf(v.x, v.x, s); s = fmaf(v.y, v.y, s);
      s = fmaf(v.z, v.z, s); s = fmaf(v.w, v.w, s);
      ushort4 o;
      o.x = f2bf(v.x); o.y = f2bf(v.y); o.z = f2bf(v.z); o.w = f2bf(v.w);
      dst[d] = o;
    }
  } else {
    ushort4 z; z.x = z.y = z.z = z.w = 0;
#pragma unroll
    for (int i = 0; i < 6; i++) dst[lane + i * 64] = z;
  }
  for (int off = 32; off; off >>= 1) s += __shfl_down(s, off, 64);
  if (lane == 0) norm[row] = s;
}

// ---------------- plain rownorm (fallback path) ----------------
__global__ __launch_bounds__(256) void rownorm_kernel(const float* __restrict__ x,
                                                      float* __restrict__ out, int rows) {
  int row = blockIdx.x;
  if (row >= rows) return;
  const float4* p4 = (const float4*)(x + (size_t)row * DDIM);
  float s = 0.f;
  for (int d = threadIdx.x; d < DDIM / 4; d += 256) {
    float4 v = p4[d];
    s = fmaf(v.x, v.x, s); s = fmaf(v.y, v.y, s);
    s = fmaf(v.z, v.z, s); s = fmaf(v.w, v.w, s);
  }
  for (int off = 32; off; off >>= 1) s += __shfl_down(s, off, 64);
  __shared__ float ls[4];
  int wid = threadIdx.x >> 6, lane = threadIdx.x & 63;
  if (lane == 0) ls[wid] = s;
  __syncthreads();
  if (threadIdx.x == 0) out[row] = ls[0] + ls[1] + ls[2] + ls[3];
}

__global__ void init_u64_kernel(unsigned long long* p, int n) {
  int i = blockIdx.x * 256 + threadIdx.x;
  if (i < n) p[i] = ~0ull;
}

// ============== 256x256 / BK=64 / 8-wave phase-pipelined MFMA min-dist ==============
__global__ __launch_bounds__(512) void mindist_mfma_kernel(
    const unsigned short* __restrict__ Ah, const unsigned short* __restrict__ Bh,
    const float* __restrict__ xnorm, const float* __restrict__ ynorm,
    unsigned long long* __restrict__ cand) {
  __shared__ char smem[131072];  // A: [0,65536) = 2 bufs x 32KB ; B: [65536,131072)

  const int t = threadIdx.x;
  const int lane = t & 63, wid = t >> 6;
  const int wm = wid >> 2, wn = wid & 3;
  const int l15 = lane & 15, g = lane >> 4;

  // bijective XCD swizzle (nwg = 4900)
  const int nwg = NRT * NCT;
  const int q8 = nwg >> 3, r8 = nwg & 7;
  int orig = blockIdx.x;
  int xcd = orig & 7, pos = orig >> 3;
  int wg = (xcd < r8 ? xcd * (q8 + 1) : r8 * (q8 + 1) + (xcd - r8) * q8) + pos;
  const int rt = wg / NCT, ct = wg % NCT;
  const int row0 = rt * 256;
  const int c0 = ct * 256;

  // fragment read address pieces (swizzle: phys_chunk = logical_chunk ^ (row&7))
  const int aBase = wm * 16384 + l15 * 128;
  const int bBase = 65536 + (wn * 64 + l15) * 128;
  int cks[2];
  cks[0] = ((0 + g) ^ (l15 & 7)) * 16;
  cks[1] = ((4 + g) ^ (l15 & 7)) * 16;

  // stage source bases: thread covers flat 16B chunk f = i*512 + t of the 256x64 tile
  const int cc = (t & 7) ^ ((t >> 3) & 7);
  const unsigned short* pa0 = Ah + (size_t)(row0 + (t >> 3)) * DDIM + cc * 8;
  const unsigned short* pb0 = Bh + (size_t)(c0 + (t >> 3)) * DDIM + cc * 8;

#define STAGEAB(kt, d)                                                                   \
  {                                                                                      \
    _Pragma("unroll") for (int i = 0; i < 4; i++) {                                      \
      __builtin_amdgcn_global_load_lds(                                                  \
          (const __attribute__((address_space(1))) void*)(pa0 + (size_t)i * (64 * DDIM) +\
                                                          (kt) * 64),                    \
          (__attribute__((address_space(3))) void*)(smem + (d) * 32768 + i * 8192 +      \
                                                    wid * 1024),                         \
          16, 0, 0);                                                                     \
    }                                                                                    \
    _Pragma("unroll") for (int i = 0; i < 4; i++) {                                      \
      __builtin_amdgcn_global_load_lds(                                                  \
          (const __attribute__((address_space(1))) void*)(pb0 + (size_t)i * (64 * DDIM) +\
                                                          (kt) * 64),                    \
          (__attribute__((address_space(3))) void*)(smem + 65536 + (d) * 32768 +         \
                                                    i * 8192 + wid * 1024),              \
          16, 0, 0);                                                                     \
    }                                                                                    \
  }

  floatx4 acc[8][4];  // [mi][nf]; row = wm*128 + mi*16
  floatx4 zz = {0.f, 0.f, 0.f, 0.f};
#pragma unroll
  for (int mi = 0; mi < 8; mi++)
#pragma unroll
    for (int nf = 0; nf < 4; nf++) acc[mi][nf] = zz;

  // prologue: stage K-tiles 0 and 1
  STAGEAB(0, 0);
  STAGEAB(1, 1);

  for (int kt = 0; kt < NKT; ++kt) {
    const int d = kt & 1;
    // gate: this K-tile's 8 loads landed (8 younger = next tile's)
    if (kt < NKT - 1) {
      asm volatile("s_waitcnt vmcnt(8)" ::: "memory");
    } else {
      asm volatile("s_waitcnt vmcnt(0)" ::: "memory");
    }
    __builtin_amdgcn_s_barrier();
    __builtin_amdgcn_sched_barrier(0);
    const int dOff = d * 32768;
    const char* sA = smem + dOff + aBase;
    const char* sB = smem + dOff + bBase;

    short8v rb[4][2];
#pragma unroll
    for (int nf = 0; nf < 4; nf++)
#pragma unroll
      for (int ks = 0; ks < 2; ks++)
        rb[nf][ks] = *(const short8v*)(sB + nf * 16 * 128 + cks[ks]);

    short8v ra[4][2][2];  // [phase][i][ks]; phase p covers mi = 2p+i
#pragma unroll
    for (int i = 0; i < 2; i++)
#pragma unroll
      for (int ks = 0; ks < 2; ks++)
        ra[0][i][ks] = *(const short8v*)(sA + i * 16 * 128 + cks[ks]);

#pragma unroll
    for (int p = 0; p < 4; p++) {
      if (p < 3) {
#pragma unroll
        for (int i = 0; i < 2; i++)
#pragma unroll
          for (int ks = 0; ks < 2; ks++)
            ra[p + 1][i][ks] =
                *(const short8v*)(sA + (2 * (p + 1) + i) * 16 * 128 + cks[ks]);
      }
      __builtin_amdgcn_s_setprio(1);
#pragma unroll
      for (int i = 0; i < 2; i++)
#pragma unroll
        for (int nf = 0; nf < 4; nf++)
#pragma unroll
          for (int ks = 0; ks < 2; ks++)
            acc[2 * p + i][nf] = __builtin_amdgcn_mfma_f32_16x16x32_bf16(
                ra[p][i][ks], rb[nf][ks], acc[2 * p + i][nf], 0, 0, 0);
      __builtin_amdgcn_s_setprio(0);
    }
    __builtin_amdgcn_sched_barrier(0);
    __builtin_amdgcn_s_barrier();
    __builtin_amdgcn_sched_barrier(0);
    if (kt < NKT - 2) STAGEAB(kt + 2, d);  // restage just-freed buffer
  }
#undef STAGEAB

  // epilogue: fold acc -> per-row packed min -> cand[row][ct]
  float yn[4];
  int colv[4];
#pragma unroll
  for (int nf = 0; nf < 4; nf++) {
    int col = c0 + wn * 64 + nf * 16 + l15;
    colv[nf] = col;
    yn[nf] = (col < MBANK) ? ynorm[col] : 0.f;
  }
#pragma unroll
  for (int mi = 0; mi < 8; mi++) {
    int rowb = row0 + wm * 128 + mi * 16 + g * 4;
#pragma unroll
    for (int q = 0; q < 4; q++) {
      float xnq = xnorm[rowb + q];
      unsigned long long best = ~0ull;
#pragma unroll
      for (int nf = 0; nf < 4; nf++) {
        if (colv[nf] < MBANK) {
          float dsq = fmaxf(xnq + yn[nf] - 2.f * acc[mi][nf][q], 0.f);
          unsigned long long p =
              ((unsigned long long)__float_as_uint(dsq) << 32) | (unsigned)colv[nf];
          best = u64min(best, p);
        }
      }
#pragma unroll
      for (int mask = 1; mask <= 8; mask <<= 1)
        best = u64min(best, __shfl_xor(best, mask, 64));
      if (l15 == 0 && rowb + q < NROWS)
        atomicMin(&cand[(size_t)(rowb + q) * NCT + ct], best);
    }
  }
}

// -------- gated fp32 re-rank of the 196 per-slot winners (value + exact index) --------
__global__ __launch_bounds__(256) void rerank_kernel(
    const float* __restrict__ emb, const float* __restrict__ mem,
    const float* __restrict__ xnorm, const float* __restrict__ ynorm,
    const unsigned long long* __restrict__ cand, float* __restrict__ ps,
    int* __restrict__ loc) {
  int row = blockIdx.x, t = threadIdx.x;
  int lane = t & 63, wave = t >> 6;
  __shared__ unsigned long long lred[4];
  __shared__ int glist[NCT];
  __shared__ int gcount;
  __shared__ float gmin;
  const unsigned long long* crow = cand + (size_t)row * NCT;
  unsigned long long mn = ~0ull;
  for (int i = t; i < NCT; i += 256) mn = u64min(mn, crow[i]);
  for (int off = 32; off; off >>= 1) {
    unsigned long long o = __shfl_down(mn, off, 64);
    mn = u64min(mn, o);
  }
  if (lane == 0) lred[wave] = mn;
  if (t == 0) gcount = 0;
  __syncthreads();
  if (t == 0) {
    unsigned long long m0 = lred[0];
    for (int w = 1; w < 4; w++) m0 = u64min(m0, lred[w]);
    gmin = __uint_as_float((unsigned)(m0 >> 32));
  }
  __syncthreads();
  float gate = gmin + 6.0f;  // >> 14 sigma of bf16 dot error
  if (t < NCT) {
    unsigned long long v = crow[t];
    float dq = __uint_as_float((unsigned)(v >> 32));
    if (dq <= gate) {
      int idx = atomicAdd(&gcount, 1);
      glist[idx] = (int)(v & 0xffffffffu);
    }
  }
  __syncthreads();
  int ng = gcount;
  float xnv = xnorm[row];
  const float4* xp = (const float4*)(emb + (size_t)row * DDIM);
  unsigned long long best = ~0ull;
  for (int gi = wave; gi < ng; gi += 4) {
    int col = glist[gi];
    const float4* yp = (const float4*)(mem + (size_t)col * DDIM);
    float s = 0.f;
    for (int d4 = lane; d4 < DDIM / 4; d4 += 64) {
      float4 a = xp[d4], b = yp[d4];
      s = fmaf(a.x, b.x, s); s = fmaf(a.y, b.y, s);
      s = fmaf(a.z, b.z, s); s = fmaf(a.w, b.w, s);
    }
    for (int off = 32; off; off >>= 1) s += __shfl_down(s, off, 64);
    if (lane == 0) {
      float dsq = fmaxf(xnv + ynorm[col] - 2.f * s, 0.f);
      unsigned long long p =
          ((unsigned long long)__float_as_uint(dsq) << 32) | (unsigned)col;
      best = u64min(best, p);
    }
  }
  if (lane == 0) lred[wave] = best;
  __syncthreads();
  if (t == 0) {
    unsigned long long b = lred[0];
    for (int w = 1; w < 4; w++) b = u64min(b, lred[w]);
    ps[row] = sqrtf(__uint_as_float((unsigned)(b >> 32)));
    loc[row] = (int)(b & 0xffffffffu);
  }
}

// ============== fallback fp32 min-distance GEMM (ws too small) ==============
#define BM 128
#define BN 128
#define DKC 16
#define FCSPLIT 16
#define FCT ((MBANK + BN - 1) / BN)
#define FCPB ((FCT + FCSPLIT - 1) / FCSPLIT)

__global__ __launch_bounds__(256) void mindist_kernel(
    const float* __restrict__ A, const float* __restrict__ Bm,
    const float* __restrict__ xnorm, const float* __restrict__ ynorm,
    unsigned long long* __restrict__ best) {
  __shared__ float Asf[DKC][BM];
  __shared__ float Bsf[DKC][BN];
  int t = threadIdx.x;
  int tx = t & 15, ty = t >> 4;
  int row0 = blockIdx.x * BM;
  int rloc[8], cloc[8];
#pragma unroll
  for (int i = 0; i < 4; i++) {
    rloc[i] = ty * 4 + i; rloc[i + 4] = 64 + ty * 4 + i;
    cloc[i] = tx * 4 + i; cloc[i + 4] = 64 + tx * 4 + i;
  }
  float xnv[8];
#pragma unroll
  for (int i = 0; i < 8; i++) xnv[i] = xnorm[row0 + rloc[i]];
  unsigned long long bestr[8];
#pragma unroll
  for (int i = 0; i < 8; i++) bestr[i] = ~0ull;
  int ct_begin = blockIdx.y * FCPB;
  int ct_end = ct_begin + FCPB; if (ct_end > FCT) ct_end = FCT;
  for (int ct = ct_begin; ct < ct_end; ++ct) {
    int c0 = ct * BN;
    float acc[8][8];
#pragma unroll
    for (int i = 0; i < 8; i++)
#pragma unroll
      for (int j = 0; j < 8; j++) acc[i][j] = 0.f;
    for (int dk = 0; dk < DDIM; dk += DKC) {
#pragma unroll
      for (int s = 0; s < 2; ++s) {
        int q = t + s * 256;
        int r = q >> 2, c4 = q & 3;
        float4 va = *(const float4*)(A + (size_t)(row0 + r) * DDIM + dk + c4 * 4);
        Asf[c4 * 4 + 0][r] = va.x; Asf[c4 * 4 + 1][r] = va.y;
        Asf[c4 * 4 + 2][r] = va.z; Asf[c4 * 4 + 3][r] = va.w;
        int col = c0 + r;
        float4 vb = make_float4(0.f, 0.f, 0.f, 0.f);
        if (col < MBANK) vb = *(const float4*)(Bm + (size_t)col * DDIM + dk + c4 * 4);
        Bsf[c4 * 4 + 0][r] = vb.x; Bsf[c4 * 4 + 1][r] = vb.y;
        Bsf[c4 * 4 + 2][r] = vb.z; Bsf[c4 * 4 + 3][r] = vb.w;
      }
      __syncthreads();
#pragma unroll
      for (int k = 0; k < DKC; k++) {
        float4 a0 = *(const float4*)&Asf[k][ty * 4];
        float4 a1 = *(const float4*)&Asf[k][64 + ty * 4];
        float4 b0 = *(const float4*)&Bsf[k][tx * 4];
        float4 b1 = *(const float4*)&Bsf[k][64 + tx * 4];
        float av[8] = {a0.x, a0.y, a0.z, a0.w, a1.x, a1.y, a1.z, a1.w};
        float bv[8] = {b0.x, b0.y, b0.z, b0.w, b1.x, b1.y, b1.z, b1.w};
#pragma unroll
        for (int i = 0; i < 8; i++)
#pragma unroll
          for (int j = 0; j < 8; j++) acc[i][j] = fmaf(av[i], bv[j], acc[i][j]);
      }
      __syncthreads();
    }
#pragma unroll
    for (int j = 0; j < 8; j++) {
      int col = c0 + cloc[j];
      if (col < MBANK) {
        float yn = ynorm[col];
#pragma unroll
        for (int i = 0; i < 8; i++) {
          float dsq = fmaxf(xnv[i] + yn - 2.f * acc[i][j], 0.f);
          unsigned long long pk =
              ((unsigned long long)__float_as_uint(dsq) << 32) | (unsigned)col;
          if (pk < bestr[i]) bestr[i] = pk;
        }
      }
    }
  }
#pragma unroll
  for (int i = 0; i < 8; i++) atomicMin(&best[row0 + rloc[i]], bestr[i]);
}

__global__ void unpack_kernel(const unsigned long long* __restrict__ best,
                              float* __restrict__ ps, int* __restrict__ loc) {
  int i = blockIdx.x * 256 + threadIdx.x;
  if (i >= NROWS) return;
  unsigned long long v = best[i];
  ps[i] = sqrtf(__uint_as_float((unsigned)(v >> 32)));
  loc[i] = (int)(v & 0xffffffffu);
}

// ---------------- per-batch argmax ----------------
__global__ __launch_bounds__(256) void argmax_kernel(const float* __restrict__ ps,
                                                     const int* __restrict__ loc,
                                                     float* __restrict__ bscore,
                                                     int* __restrict__ bfrow,
                                                     int* __restrict__ bnn) {
  int b = blockIdx.x, t = threadIdx.x;
  unsigned long long bp = 0;
  for (int p = t; p < PP; p += 256) {
    unsigned long long pk = ((unsigned long long)__float_as_uint(ps[b * PP + p]) << 32) |
                            (unsigned)(0xffffffffu - (unsigned)p);
    if (pk > bp) bp = pk;
  }
  for (int off = 32; off; off >>= 1) {
    unsigned long long o = __shfl_down(bp, off, 64);
    if (o > bp) bp = o;
  }
  __shared__ unsigned long long ls[4];
  int wid = t >> 6, lane = t & 63;
  if (lane == 0) ls[wid] = bp;
  __syncthreads();
  if (t == 0) {
    for (int w = 1; w < 4; w++) if (ls[w] > ls[0]) ls[0] = ls[w];
    unsigned p = 0xffffffffu - (unsigned)(ls[0] & 0xffffffffu);
    bscore[b] = __uint_as_float((unsigned)(ls[0] >> 32));
    bfrow[b] = b * PP + (int)p;
    bnn[b] = loc[b * PP + (int)p];
  }
}

// ---------------- d2: nn_sample vs memory bank ----------------
__global__ __launch_bounds__(256) void d2_kernel(const float* __restrict__ mem,
                                                 const float* __restrict__ ynorm,
                                                 const int* __restrict__ bnn,
                                                 float* __restrict__ d2) {
  __shared__ float nn8[NB][DDIM];
  __shared__ float nnorm[NB];
  for (int e = threadIdx.x; e < NB * DDIM; e += 256) {
    int b = e / DDIM, d = e % DDIM;
    nn8[b][d] = mem[(size_t)bnn[b] * DDIM + d];
  }
  if (threadIdx.x < NB) nnorm[threadIdx.x] = ynorm[bnn[threadIdx.x]];
  __syncthreads();
  int wid = threadIdx.x >> 6, lane = threadIdx.x & 63;
  int gw = blockIdx.x * 4 + wid;
  int nw = gridDim.x * 4;
  for (int m = gw; m < MBANK; m += nw) {
    const float4* mp4 = (const float4*)(mem + (size_t)m * DDIM);
    float acc[NB];
#pragma unroll
    for (int b = 0; b < NB; b++) acc[b] = 0.f;
    for (int d4 = lane; d4 < DDIM / 4; d4 += 64) {
      float4 v = mp4[d4];
#pragma unroll
      for (int b = 0; b < NB; b++) {
        float4 w = *(const float4*)&nn8[b][d4 * 4];
        acc[b] = fmaf(v.x, w.x, acc[b]); acc[b] = fmaf(v.y, w.y, acc[b]);
        acc[b] = fmaf(v.z, w.z, acc[b]); acc[b] = fmaf(v.w, w.w, acc[b]);
      }
    }
    float yn = ynorm[m];
#pragma unroll
    for (int b = 0; b < NB; b++) {
      float r = acc[b];
      for (int off = 32; off; off >>= 1) r += __shfl_down(r, off, 64);
      if (lane == 0) d2[(size_t)b * MBANK + m] = sqrtf(fmaxf(nnorm[b] + yn - 2.f * r, 0.f));
    }
  }
}

// ------- single-pass top-9 + softmax weight + pred score -------
__global__ __launch_bounds__(256) void topk_kernel(
    const float* __restrict__ emb, const float* __restrict__ mem,
    const float* __restrict__ xnorm, const float* __restrict__ ynorm,
    const float* __restrict__ d2, const float* __restrict__ bscore,
    const int* __restrict__ bfrow, float* __restrict__ pred) {
  int b = blockIdx.x, t = threadIdx.x;
  __shared__ unsigned long long ls9[256][9];
  __shared__ float fred[4];
  __shared__ int supp[9];
  __shared__ float d3s[9];
  const float* row = d2 + (size_t)b * MBANK;
  // per-thread sorted (ascending) top-9
  unsigned long long a0 = ~0ull, a1 = ~0ull, a2 = ~0ull, a3 = ~0ull, a4 = ~0ull,
                     a5 = ~0ull, a6 = ~0ull, a7 = ~0ull, a8 = ~0ull;
  for (int m = t; m < MBANK; m += 256) {
    unsigned long long pk = ((unsigned long long)__float_as_uint(row[m]) << 32) | (unsigned)m;
    if (pk < a8) {
      a8 = pk;
      unsigned long long tv;
#define CSWP(x, y) if (y < x) { tv = x; x = y; y = tv; }
      CSWP(a7, a8) CSWP(a6, a7) CSWP(a5, a6) CSWP(a4, a5)
      CSWP(a3, a4) CSWP(a2, a3) CSWP(a1, a2) CSWP(a0, a1)
#undef CSWP
    }
  }
  ls9[t][0] = a0; ls9[t][1] = a1; ls9[t][2] = a2; ls9[t][3] = a3; ls9[t][4] = a4;
  ls9[t][5] = a5; ls9[t][6] = a6; ls9[t][7] = a7; ls9[t][8] = a8;
  __syncthreads();
  for (int s = 128; s >= 1; s >>= 1) {
    if (t < s) {
      unsigned long long outv[9];
      int i = 0, j = 0;
#pragma unroll
      for (int k = 0; k < 9; k++) {
        unsigned long long x = ls9[t][i], y = ls9[t + s][j];
        if (x <= y) { outv[k] = x; i++; } else { outv[k] = y; j++; }
      }
#pragma unroll
      for (int k = 0; k < 9; k++) ls9[t][k] = outv[k];
    }
    __syncthreads();
  }
  if (t < 9) supp[t] = (int)(ls9[0][t] & 0xffffffffu);
  __syncthreads();
  int frow = bfrow[b];
  const float* x = emb + (size_t)frow * DDIM;
  float xnv = xnorm[frow];
  for (int k = 0; k < 9; k++) {
    const float* y = mem + (size_t)supp[k] * DDIM;
    float s = 0.f;
    for (int d = t; d < DDIM; d += 256) s = fmaf(x[d], y[d], s);
    for (int off = 32; off; off >>= 1) s += __shfl_down(s, off, 64);
    if ((t & 63) == 0) fred[t >> 6] = s;
    __syncthreads();
    if (t == 0) {
      float dot = fred[0] + fred[1] + fred[2] + fred[3];
      d3s[k] = sqrtf(fmaxf(xnv - 2.f * dot + ynorm[supp[k]], 0.f));
    }
    __syncthreads();
  }
  if (t == 0) {
    float mx = d3s[0];
    for (int k = 1; k < 9; k++) mx = fmaxf(mx, d3s[k]);
    float sum = 0.f;
    for (int k = 0; k < 9; k++) sum += expf(d3s[k] - mx);
    float w = 1.f - expf(d3s[0] - mx) / sum;
    pred[b] = w * bscore[b];
  }
}

// ---------------- gaussian weights ----------------
__global__ void gauss_kernel(float* __restrict__ g) {
  __shared__ float tmp[KS];
  int t = threadIdx.x;
  if (t < KS) {
    float x = (float)t - (float)(KS - 1) * 0.5f;
    tmp[t] = __expf(-(x * x) / 32.0f);
  }
  __syncthreads();
  if (t == 0) {
    float s = 0.f;
    for (int j = 0; j < KS; j++) s += tmp[j];
    for (int j = 0; j < KS; j++) g[j] = tmp[j] / s;
  }
}

// ---------------- bilinear resize 28 -> 224 ----------------
__global__ __launch_bounds__(256) void resize_kernel(const float* __restrict__ ps,
                                                     float* __restrict__ out) {
  int idx = blockIdx.x * 256 + threadIdx.x;
  if (idx >= NB * HW * HW) return;
  int x = idx % HW, y = (idx / HW) % HW, b = idx / (HW * HW);
  float sx = (x + 0.5f) * 0.125f - 0.5f;
  float sy = (y + 0.5f) * 0.125f - 0.5f;
  int x0 = (int)floorf(sx), y0 = (int)floorf(sy);
  float fx = sx - x0, fy = sy - y0;
  int x0c = min(max(x0, 0), 27), x1c = min(max(x0 + 1, 0), 27);
  int y0c = min(max(y0, 0), 27), y1c = min(max(y0 + 1, 0), 27);
  const float* p = ps + b * PP;
  float v00 = p[y0c * 28 + x0c], v01 = p[y0c * 28 + x1c];
  float v10 = p[y1c * 28 + x0c], v11 = p[y1c * 28 + x1c];
  out[idx] = v00 * (1.f - fy) * (1.f - fx) + v01 * (1.f - fy) * fx +
             v10 * fy * (1.f - fx) + v11 * fy * fx;
}

// ---------------- separable gaussian blur, reflect padding ----------------
__device__ __forceinline__ int reflect224(int i) {
  if (i < 0) i = -i;
  if (i > 223) i = 446 - i;
  return i;
}

__global__ __launch_bounds__(256) void blurv_kernel(const float* __restrict__ in,
                                                    const float* __restrict__ g,
                                                    float* __restrict__ out) {
  __shared__ float gk[KS];
  if (threadIdx.x < KS) gk[threadIdx.x] = g[threadIdx.x];
  __syncthreads();
  int idx = blockIdx.x * 256 + threadIdx.x;
  if (idx >= NB * HW * HW) return;
  int x = idx % HW, y = (idx / HW) % HW, b = idx / (HW * HW);
  const float* base = in + (size_t)b * HW * HW;
  float s = 0.f;
#pragma unroll
  for (int j = 0; j < KS; j++) {
    int yy = reflect224(y - PAD + j);
    s = fmaf(gk[j], base[yy * HW + x], s);
  }
  out[idx] = s;
}

__global__ __launch_bounds__(256) void blurh_kernel(const float* __restrict__ in,
                                                    const float* __restrict__ g,
                                                    float* __restrict__ out) {
  __shared__ float gk[KS];
  if (threadIdx.x < KS) gk[threadIdx.x] = g[threadIdx.x];
  __syncthreads();
  int idx = blockIdx.x * 256 + threadIdx.x;
  if (idx >= NB * HW * HW) return;
  int x = idx % HW, y = (idx / HW) % HW, b = idx / (HW * HW);
  const float* base = in + (size_t)b * HW * HW;
  float s = 0.f;
#pragma unroll
  for (int j = 0; j < KS; j++) {
    int xx = reflect224(x - PAD + j);
    s = fmaf(gk[j], base[y * HW + xx], s);
  }
  out[idx] = s;
}

// ---------------- host ----------------
extern "C" void kernel_launch(void* const* d_in, const int* in_sizes, int n_in,
                              void* d_out, int out_size, void* d_ws, size_t ws_size,
                              hipStream_t stream) {
  const float* emb = (const float*)d_in[0];
  const float* mem = (const float*)d_in[1];
  float* out = (float*)d_out;

  char* ws = (char*)d_ws;
  size_t off = 0;
  auto alloc = [&](size_t bytes) -> void* {
    void* p = ws + off;
    off += (bytes + 255) & ~(size_t)255;
    return p;
  };
  float* ynorm = (float*)alloc((size_t)NCOLPAD * 4);
  float* xnorm = (float*)alloc((size_t)NROWPAD * 4);
  unsigned long long* cand =
      (unsigned long long*)alloc((size_t)NROWS * NCT * 8);
  float* ps = (float*)alloc(NROWS * 4);
  int* loc = (int*)alloc(NROWS * 4);
  float* bscore = (float*)alloc(NB * 4);
  int* bfrow = (int*)alloc(NB * 4);
  int* bnn = (int*)alloc(NB * 4);
  float* d2 = (float*)alloc((size_t)NB * MBANK * 4);
  float* g = (float*)alloc(KS * 4);
  float* rsz = (float*)alloc((size_t)NB * HW * HW * 4);
  float* tmp = (float*)alloc((size_t)NB * HW * HW * 4);
  unsigned short* emb_h = (unsigned short*)alloc((size_t)NROWPAD * DDIM * 2);
  unsigned short* mem_h = (unsigned short*)alloc((size_t)NCOLPAD * DDIM * 2);
  size_t full_need = off;

  bool fast = (ws_size >= full_need);

  if (fast) {
    convnorm_kernel<<<NCOLPAD / 4, 256, 0, stream>>>(mem, mem_h, ynorm, MBANK, NCOLPAD);
    convnorm_kernel<<<NROWPAD / 4, 256, 0, stream>>>(emb, emb_h, xnorm, NROWS, NROWPAD);
    init_u64_kernel<<<(NROWS * NCT + 255) / 256, 256, 0, stream>>>(cand, NROWS * NCT);
    mindist_mfma_kernel<<<NRT * NCT, 512, 0, stream>>>(emb_h, mem_h, xnorm, ynorm, cand);
    rerank_kernel<<<NROWS, 256, 0, stream>>>(emb, mem, xnorm, ynorm, cand, ps, loc);
    argmax_kernel<<<NB, 256, 0, stream>>>(ps, loc, bscore, bfrow, bnn);
  } else {
    rownorm_kernel<<<MBANK, 256, 0, stream>>>(mem, ynorm, MBANK);
    rownorm_kernel<<<NROWS, 256, 0, stream>>>(emb, xnorm, NROWS);
    unsigned long long* best = cand;  // alias
    init_u64_kernel<<<(NROWS + 255) / 256, 256, 0, stream>>>(best, NROWS);
    mindist_kernel<<<dim3(NROWS / BM, FCSPLIT), 256, 0, stream>>>(emb, mem, xnorm, ynorm,
                                                                  best);
    unpack_kernel<<<(NROWS + 255) / 256, 256, 0, stream>>>(best, ps, loc);
    argmax_kernel<<<NB, 256, 0, stream>>>(ps, loc, bscore, bfrow, bnn);
  }

  d2_kernel<<<400, 256, 0, stream>>>(mem, ynorm, bnn, d2);
  topk_kernel<<<NB, 256, 0, stream>>>(emb, mem, xnorm, ynorm, d2, bscore, bfrow,
                                      out + (size_t)NB * HW * HW);
  gauss_kernel<<<1, 64, 0, stream>>>(g);
  resize_kernel<<<(NB * HW * HW + 255) / 256, 256, 0, stream>>>(ps, rsz);
  blurv_kernel<<<(NB * HW * HW + 255) / 256, 256, 0, stream>>>(rsz, g, tmp);
  blurh_kernel<<<(NB * HW * HW + 255) / 256, 256, 0, stream>>>(tmp, g, out);
}

// Round 5
// 1671.406 us; speedup vs baseline: 12.5543x; 1.0245x over previous
//
#include <hip/hip_runtime.h>
#include <cstdint>
#include <cstddef>

#define DDIM 1536
#define NROWS 6272      // B*P*P
#define NROWPAD 6400    // >= 55*112+128, zero-padded rows
#define MBANK 50000
#define NCOLPAD 50176   // 196*256
#define MT 112          // row-tile (56*112 = 6272 exactly; 56 = 8 XCD * 7)
#define NRT 56
#define NCT 196         // 256-col panels
#define NKS 48          // 1536 / 32
#define NB 8
#define PP 784
#define HW 224
#define KS 33
#define PAD 16

typedef __attribute__((ext_vector_type(8))) short short8v;
typedef __attribute__((ext_vector_type(4))) float floatx4;

__device__ __forceinline__ unsigned long long u64min(unsigned long long a, unsigned long long b) {
  return a < b ? a : b;
}

// ---------------- fp32 -> bf16 (RNE) ----------------
__device__ __forceinline__ unsigned short f2bf(float f) {
  unsigned u = __float_as_uint(f);
  return (unsigned short)((u + 0x7fffu + ((u >> 16) & 1u)) >> 16);
}

// ---------------- fused convert + row norm, wave-per-row ----------------
__global__ __launch_bounds__(256) void convnorm_kernel(const float* __restrict__ in,
                                                       unsigned short* __restrict__ out,
                                                       float* __restrict__ norm,
                                                       int valid_rows, int total_rows) {
  int row = blockIdx.x * 4 + (threadIdx.x >> 6);
  int lane = threadIdx.x & 63;
  if (row >= total_rows) return;
  ushort4* dst = (ushort4*)(out + (size_t)row * DDIM);
  float s = 0.f;
  if (row < valid_rows) {
    const float4* src = (const float4*)(in + (size_t)row * DDIM);
#pragma unroll
    for (int i = 0; i < 6; i++) {
      int d = lane + i * 64;
      float4 v = src[d];
      s = fmaf(v.x, v.x, s); s = fmaf(v.y, v.y, s);
      s = fmaf(v.z, v.z, s); s = fmaf(v.w, v.w, s);
      ushort4 o;
      o.x = f2bf(v.x); o.y = f2bf(v.y); o.z = f2bf(v.z); o.w = f2bf(v.w);
      dst[d] = o;
    }
  } else {
    ushort4 z; z.x = z.y = z.z = z.w = 0;
#pragma unroll
    for (int i = 0; i < 6; i++) dst[lane + i * 64] = z;
  }
  for (int off = 32; off; off >>= 1) s += __shfl_down(s, off, 64);
  if (lane == 0) norm[row] = s;
}

// ---------------- plain rownorm (fallback path) ----------------
__global__ __launch_bounds__(256) void rownorm_kernel(const float* __restrict__ x,
                                                      float* __restrict__ out, int rows) {
  int row = blockIdx.x;
  if (row >= rows) return;
  const float4* p4 = (const float4*)(x + (size_t)row * DDIM);
  float s = 0.f;
  for (int d = threadIdx.x; d < DDIM / 4; d += 256) {
    float4 v = p4[d];
    s = fmaf(v.x, v.x, s); s = fmaf(v.y, v.y, s);
    s = fmaf(v.z, v.z, s); s = fmaf(v.w, v.w, s);
  }
  for (int off = 32; off; off >>= 1) s += __shfl_down(s, off, 64);
  __shared__ float ls[4];
  int wid = threadIdx.x >> 6, lane = threadIdx.x & 63;
  if (lane == 0) ls[wid] = s;
  __syncthreads();
  if (threadIdx.x == 0) out[row] = ls[0] + ls[1] + ls[2] + ls[3];
}

__global__ void init_u64_kernel(unsigned long long* p, int n) {
  int i = blockIdx.x * 256 + threadIdx.x;
  if (i < n) p[i] = ~0ull;
}

// ============== 112x256 / BK=32 / 4-wave / 2-blocks-per-CU MFMA min-dist ==============
// XCD-partitioned: xcd owns 7 row-tiles (A L2-resident), sweeps ct-major (B panel shared).
__global__ __launch_bounds__(256, 2) void mindist_mfma_kernel(
    const unsigned short* __restrict__ Ah, const unsigned short* __restrict__ Bh,
    const float* __restrict__ xnorm, const float* __restrict__ ynorm,
    unsigned long long* __restrict__ cand) {
  // A: 2 bufs x 8KB (128 rows x 64B); B: 2 bufs x 16KB (256 rows x 64B)
  __shared__ char smem[49152];

  const int t = threadIdx.x;
  const int lane = t & 63, wid = t >> 6;  // 4 waves; wave = 112 rows x 64 cols
  const int wn = wid;
  const int l15 = lane & 15, g = lane >> 4;

  // XCD-balanced mapping: 10976 blocks = 8 XCD x (7 rt x 196 ct), ct-major per XCD
  const int bid = blockIdx.x;
  const int xcd = bid & 7, p = bid >> 3;
  const int ct = p / 7;
  const int rt = xcd * 7 + (p % 7);
  const int row0 = rt * MT;
  const int c0 = ct * 256;

  // LDS fragment read offset (64B rows, swizzle: chunk ^= (r&3)^((r>>2)&3))
  const int swz = l15 * 64 + ((g ^ (l15 & 3) ^ ((l15 >> 2) & 3)) << 4);

  // staging source: thread covers 16B chunk f = i*256 + t; r = f>>2, logical chunk
  // cl = (f&3) ^ ((f>>2)&3) ^ ((f>>4)&3)  (i-independent since i*256 keeps bits 2..5 mod 4)
  const int cl = (t & 3) ^ ((t >> 2) & 3) ^ ((t >> 4) & 3);
  const int rA = t >> 2;  // + i*64
  const unsigned short* pa0 = Ah + (size_t)(row0 + rA) * DDIM + cl * 8;
  const unsigned short* pb0 = Bh + (size_t)(c0 + rA) * DDIM + cl * 8;

#define STAGE(kt, d)                                                                     \
  {                                                                                      \
    _Pragma("unroll") for (int i = 0; i < 2; i++) {                                      \
      __builtin_amdgcn_global_load_lds(                                                  \
          (const __attribute__((address_space(1))) void*)(pa0 + (size_t)i * (64 * DDIM) +\
                                                          (kt) * 32),                    \
          (__attribute__((address_space(3))) void*)(smem + (d) * 8192 +                  \
                                                    (i * 256 + wid * 64) * 16),          \
          16, 0, 0);                                                                     \
    }                                                                                    \
    _Pragma("unroll") for (int i = 0; i < 4; i++) {                                      \
      __builtin_amdgcn_global_load_lds(                                                  \
          (const __attribute__((address_space(1))) void*)(pb0 + (size_t)i * (64 * DDIM) +\
                                                          (kt) * 32),                    \
          (__attribute__((address_space(3))) void*)(smem + 16384 + (d) * 16384 +         \
                                                    (i * 256 + wid * 64) * 16),          \
          16, 0, 0);                                                                     \
    }                                                                                    \
  }

  floatx4 acc[7][4];  // [mi][nf]; row = mi*16, col = wn*64 + nf*16
  floatx4 zz = {0.f, 0.f, 0.f, 0.f};
#pragma unroll
  for (int mi = 0; mi < 7; mi++)
#pragma unroll
    for (int nf = 0; nf < 4; nf++) acc[mi][nf] = zz;

  STAGE(0, 0);
  STAGE(1, 1);

  for (int kt = 0; kt < NKS; ++kt) {
    const int d = kt & 1;
    if (kt < NKS - 1) {
      asm volatile("s_waitcnt vmcnt(6)" ::: "memory");
    } else {
      asm volatile("s_waitcnt vmcnt(0)" ::: "memory");
    }
    __builtin_amdgcn_sched_barrier(0);
    __builtin_amdgcn_s_barrier();
    __builtin_amdgcn_sched_barrier(0);

    const char* sA = smem + d * 8192 + swz;
    const char* sB = smem + 16384 + d * 16384 + wn * 4096 + swz;
    short8v rb[4], ra[7];
#pragma unroll
    for (int nf = 0; nf < 4; nf++) rb[nf] = *(const short8v*)(sB + nf * 1024);
#pragma unroll
    for (int mi = 0; mi < 7; mi++) ra[mi] = *(const short8v*)(sA + mi * 1024);

    __builtin_amdgcn_s_setprio(1);
#pragma unroll
    for (int mi = 0; mi < 7; mi++)
#pragma unroll
      for (int nf = 0; nf < 4; nf++)
        acc[mi][nf] =
            __builtin_amdgcn_mfma_f32_16x16x32_bf16(ra[mi], rb[nf], acc[mi][nf], 0, 0, 0);
    __builtin_amdgcn_s_setprio(0);

    __builtin_amdgcn_sched_barrier(0);
    __builtin_amdgcn_s_barrier();
    __builtin_amdgcn_sched_barrier(0);
    if (kt < NKS - 2) STAGE(kt + 2, d);
  }
#undef STAGE

  // epilogue: fold acc -> per-row packed min -> atomicMin cand[row][ct]
  float yn[4];
  int colv[4];
#pragma unroll
  for (int nf = 0; nf < 4; nf++) {
    int col = c0 + wn * 64 + nf * 16 + l15;
    colv[nf] = col;
    yn[nf] = (col < MBANK) ? ynorm[col] : 0.f;
  }
#pragma unroll
  for (int mi = 0; mi < 7; mi++) {
    int rowb = row0 + mi * 16 + g * 4;
#pragma unroll
    for (int q = 0; q < 4; q++) {
      float xnq = xnorm[rowb + q];
      unsigned long long best = ~0ull;
#pragma unroll
      for (int nf = 0; nf < 4; nf++) {
        if (colv[nf] < MBANK) {
          float dsq = fmaxf(xnq + yn[nf] - 2.f * acc[mi][nf][q], 0.f);
          unsigned long long pk =
              ((unsigned long long)__float_as_uint(dsq) << 32) | (unsigned)colv[nf];
          best = u64min(best, pk);
        }
      }
#pragma unroll
      for (int mask = 1; mask <= 8; mask <<= 1)
        best = u64min(best, __shfl_xor(best, mask, 64));
      if (l15 == 0)
        atomicMin(&cand[(size_t)(rowb + q) * NCT + ct], best);
    }
  }
}

// -------- gated fp32 re-rank of the 196 per-slot winners (value + exact index) --------
__global__ __launch_bounds__(256) void rerank_kernel(
    const float* __restrict__ emb, const float* __restrict__ mem,
    const float* __restrict__ xnorm, const float* __restrict__ ynorm,
    const unsigned long long* __restrict__ cand, float* __restrict__ ps,
    int* __restrict__ loc) {
  int row = blockIdx.x, t = threadIdx.x;
  int lane = t & 63, wave = t >> 6;
  __shared__ unsigned long long lred[4];
  __shared__ int glist[NCT];
  __shared__ int gcount;
  __shared__ float gmin;
  const unsigned long long* crow = cand + (size_t)row * NCT;
  unsigned long long mn = ~0ull;
  for (int i = t; i < NCT; i += 256) mn = u64min(mn, crow[i]);
  for (int off = 32; off; off >>= 1) {
    unsigned long long o = __shfl_down(mn, off, 64);
    mn = u64min(mn, o);
  }
  if (lane == 0) lred[wave] = mn;
  if (t == 0) gcount = 0;
  __syncthreads();
  if (t == 0) {
    unsigned long long m0 = lred[0];
    for (int w = 1; w < 4; w++) m0 = u64min(m0, lred[w]);
    gmin = __uint_as_float((unsigned)(m0 >> 32));
  }
  __syncthreads();
  float gate = gmin + 6.0f;  // >> 14 sigma of bf16 dot error
  if (t < NCT) {
    unsigned long long v = crow[t];
    float dq = __uint_as_float((unsigned)(v >> 32));
    if (dq <= gate) {
      int idx = atomicAdd(&gcount, 1);
      glist[idx] = (int)(v & 0xffffffffu);
    }
  }
  __syncthreads();
  int ng = gcount;
  float xnv = xnorm[row];
  const float4* xp = (const float4*)(emb + (size_t)row * DDIM);
  unsigned long long best = ~0ull;
  for (int gi = wave; gi < ng; gi += 4) {
    int col = glist[gi];
    const float4* yp = (const float4*)(mem + (size_t)col * DDIM);
    float s = 0.f;
    for (int d4 = lane; d4 < DDIM / 4; d4 += 64) {
      float4 a = xp[d4], b = yp[d4];
      s = fmaf(a.x, b.x, s); s = fmaf(a.y, b.y, s);
      s = fmaf(a.z, b.z, s); s = fmaf(a.w, b.w, s);
    }
    for (int off = 32; off; off >>= 1) s += __shfl_down(s, off, 64);
    if (lane == 0) {
      float dsq = fmaxf(xnv + ynorm[col] - 2.f * s, 0.f);
      unsigned long long pk =
          ((unsigned long long)__float_as_uint(dsq) << 32) | (unsigned)col;
      best = u64min(best, pk);
    }
  }
  if (lane == 0) lred[wave] = best;
  __syncthreads();
  if (t == 0) {
    unsigned long long b = lred[0];
    for (int w = 1; w < 4; w++) b = u64min(b, lred[w]);
    ps[row] = sqrtf(__uint_as_float((unsigned)(b >> 32)));
    loc[row] = (int)(b & 0xffffffffu);
  }
}

// ============== fallback fp32 min-distance GEMM (ws too small) ==============
#define BM 128
#define BN 128
#define DKC 16
#define FCSPLIT 16
#define FCT ((MBANK + BN - 1) / BN)
#define FCPB ((FCT + FCSPLIT - 1) / FCSPLIT)

__global__ __launch_bounds__(256) void mindist_kernel(
    const float* __restrict__ A, const float* __restrict__ Bm,
    const float* __restrict__ xnorm, const float* __restrict__ ynorm,
    unsigned long long* __restrict__ best) {
  __shared__ float Asf[DKC][BM];
  __shared__ float Bsf[DKC][BN];
  int t = threadIdx.x;
  int tx = t & 15, ty = t >> 4;
  int row0 = blockIdx.x * BM;
  int rloc[8], cloc[8];
#pragma unroll
  for (int i = 0; i < 4; i++) {
    rloc[i] = ty * 4 + i; rloc[i + 4] = 64 + ty * 4 + i;
    cloc[i] = tx * 4 + i; cloc[i + 4] = 64 + tx * 4 + i;
  }
  float xnv[8];
#pragma unroll
  for (int i = 0; i < 8; i++) xnv[i] = xnorm[row0 + rloc[i]];
  unsigned long long bestr[8];
#pragma unroll
  for (int i = 0; i < 8; i++) bestr[i] = ~0ull;
  int ct_begin = blockIdx.y * FCPB;
  int ct_end = ct_begin + FCPB; if (ct_end > FCT) ct_end = FCT;
  for (int ct = ct_begin; ct < ct_end; ++ct) {
    int c0 = ct * BN;
    float acc[8][8];
#pragma unroll
    for (int i = 0; i < 8; i++)
#pragma unroll
      for (int j = 0; j < 8; j++) acc[i][j] = 0.f;
    for (int dk = 0; dk < DDIM; dk += DKC) {
#pragma unroll
      for (int s = 0; s < 2; ++s) {
        int q = t + s * 256;
        int r = q >> 2, c4 = q & 3;
        float4 va = *(const float4*)(A + (size_t)(row0 + r) * DDIM + dk + c4 * 4);
        Asf[c4 * 4 + 0][r] = va.x; Asf[c4 * 4 + 1][r] = va.y;
        Asf[c4 * 4 + 2][r] = va.z; Asf[c4 * 4 + 3][r] = va.w;
        int col = c0 + r;
        float4 vb = make_float4(0.f, 0.f, 0.f, 0.f);
        if (col < MBANK) vb = *(const float4*)(Bm + (size_t)col * DDIM + dk + c4 * 4);
        Bsf[c4 * 4 + 0][r] = vb.x; Bsf[c4 * 4 + 1][r] = vb.y;
        Bsf[c4 * 4 + 2][r] = vb.z; Bsf[c4 * 4 + 3][r] = vb.w;
      }
      __syncthreads();
#pragma unroll
      for (int k = 0; k < DKC; k++) {
        float4 a0 = *(const float4*)&Asf[k][ty * 4];
        float4 a1 = *(const float4*)&Asf[k][64 + ty * 4];
        float4 b0 = *(const float4*)&Bsf[k][tx * 4];
        float4 b1 = *(const float4*)&Bsf[k][64 + tx * 4];
        float av[8] = {a0.x, a0.y, a0.z, a0.w, a1.x, a1.y, a1.z, a1.w};
        float bv[8] = {b0.x, b0.y, b0.z, b0.w, b1.x, b1.y, b1.z, b1.w};
#pragma unroll
        for (int i = 0; i < 8; i++)
#pragma unroll
          for (int j = 0; j < 8; j++) acc[i][j] = fmaf(av[i], bv[j], acc[i][j]);
      }
      __syncthreads();
    }
#pragma unroll
    for (int j = 0; j < 8; j++) {
      int col = c0 + cloc[j];
      if (col < MBANK) {
        float yn = ynorm[col];
#pragma unroll
        for (int i = 0; i < 8; i++) {
          float dsq = fmaxf(xnv[i] + yn - 2.f * acc[i][j], 0.f);
          unsigned long long pk =
              ((unsigned long long)__float_as_uint(dsq) << 32) | (unsigned)col;
          if (pk < bestr[i]) bestr[i] = pk;
        }
      }
    }
  }
#pragma unroll
  for (int i = 0; i < 8; i++) atomicMin(&best[row0 + rloc[i]], bestr[i]);
}

__global__ void unpack_kernel(const unsigned long long* __restrict__ best,
                              float* __restrict__ ps, int* __restrict__ loc) {
  int i = blockIdx.x * 256 + threadIdx.x;
  if (i >= NROWS) return;
  unsigned long long v = best[i];
  ps[i] = sqrtf(__uint_as_float((unsigned)(v >> 32)));
  loc[i] = (int)(v & 0xffffffffu);
}

// ---------------- per-batch argmax ----------------
__global__ __launch_bounds__(256) void argmax_kernel(const float* __restrict__ ps,
                                                     const int* __restrict__ loc,
                                                     float* __restrict__ bscore,
                                                     int* __restrict__ bfrow,
                                                     int* __restrict__ bnn) {
  int b = blockIdx.x, t = threadIdx.x;
  unsigned long long bp = 0;
  for (int p = t; p < PP; p += 256) {
    unsigned long long pk = ((unsigned long long)__float_as_uint(ps[b * PP + p]) << 32) |
                            (unsigned)(0xffffffffu - (unsigned)p);
    if (pk > bp) bp = pk;
  }
  for (int off = 32; off; off >>= 1) {
    unsigned long long o = __shfl_down(bp, off, 64);
    if (o > bp) bp = o;
  }
  __shared__ unsigned long long ls[4];
  int wid = t >> 6, lane = t & 63;
  if (lane == 0) ls[wid] = bp;
  __syncthreads();
  if (t == 0) {
    for (int w = 1; w < 4; w++) if (ls[w] > ls[0]) ls[0] = ls[w];
    unsigned p = 0xffffffffu - (unsigned)(ls[0] & 0xffffffffu);
    bscore[b] = __uint_as_float((unsigned)(ls[0] >> 32));
    bfrow[b] = b * PP + (int)p;
    bnn[b] = loc[b * PP + (int)p];
  }
}

// ---------------- d2: nn_sample vs memory bank ----------------
__global__ __launch_bounds__(256) void d2_kernel(const float* __restrict__ mem,
                                                 const float* __restrict__ ynorm,
                                                 const int* __restrict__ bnn,
                                                 float* __restrict__ d2) {
  __shared__ float nn8[NB][DDIM];
  __shared__ float nnorm[NB];
  for (int e = threadIdx.x; e < NB * DDIM; e += 256) {
    int b = e / DDIM, d = e % DDIM;
    nn8[b][d] = mem[(size_t)bnn[b] * DDIM + d];
  }
  if (threadIdx.x < NB) nnorm[threadIdx.x] = ynorm[bnn[threadIdx.x]];
  __syncthreads();
  int wid = threadIdx.x >> 6, lane = threadIdx.x & 63;
  int gw = blockIdx.x * 4 + wid;
  int nw = gridDim.x * 4;
  for (int m = gw; m < MBANK; m += nw) {
    const float4* mp4 = (const float4*)(mem + (size_t)m * DDIM);
    float acc[NB];
#pragma unroll
    for (int b = 0; b < NB; b++) acc[b] = 0.f;
    for (int d4 = lane; d4 < DDIM / 4; d4 += 64) {
      float4 v = mp4[d4];
#pragma unroll
      for (int b = 0; b < NB; b++) {
        float4 w = *(const float4*)&nn8[b][d4 * 4];
        acc[b] = fmaf(v.x, w.x, acc[b]); acc[b] = fmaf(v.y, w.y, acc[b]);
        acc[b] = fmaf(v.z, w.z, acc[b]); acc[b] = fmaf(v.w, w.w, acc[b]);
      }
    }
    float yn = ynorm[m];
#pragma unroll
    for (int b = 0; b < NB; b++) {
      float r = acc[b];
      for (int off = 32; off; off >>= 1) r += __shfl_down(r, off, 64);
      if (lane == 0) d2[(size_t)b * MBANK + m] = sqrtf(fmaxf(nnorm[b] + yn - 2.f * r, 0.f));
    }
  }
}

// ------- single-pass top-9 + softmax weight + pred score -------
__global__ __launch_bounds__(256) void topk_kernel(
    const float* __restrict__ emb, const float* __restrict__ mem,
    const float* __restrict__ xnorm, const float* __restrict__ ynorm,
    const float* __restrict__ d2, const float* __restrict__ bscore,
    const int* __restrict__ bfrow, float* __restrict__ pred) {
  int b = blockIdx.x, t = threadIdx.x;
  __shared__ unsigned long long ls9[256][9];
  __shared__ float fred[4];
  __shared__ int supp[9];
  __shared__ float d3s[9];
  const float* row = d2 + (size_t)b * MBANK;
  unsigned long long a0 = ~0ull, a1 = ~0ull, a2 = ~0ull, a3 = ~0ull, a4 = ~0ull,
                     a5 = ~0ull, a6 = ~0ull, a7 = ~0ull, a8 = ~0ull;
  for (int m = t; m < MBANK; m += 256) {
    unsigned long long pk = ((unsigned long long)__float_as_uint(row[m]) << 32) | (unsigned)m;
    if (pk < a8) {
      a8 = pk;
      unsigned long long tv;
#define CSWP(x, y) if (y < x) { tv = x; x = y; y = tv; }
      CSWP(a7, a8) CSWP(a6, a7) CSWP(a5, a6) CSWP(a4, a5)
      CSWP(a3, a4) CSWP(a2, a3) CSWP(a1, a2) CSWP(a0, a1)
#undef CSWP
    }
  }
  ls9[t][0] = a0; ls9[t][1] = a1; ls9[t][2] = a2; ls9[t][3] = a3; ls9[t][4] = a4;
  ls9[t][5] = a5; ls9[t][6] = a6; ls9[t][7] = a7; ls9[t][8] = a8;
  __syncthreads();
  for (int s = 128; s >= 1; s >>= 1) {
    if (t < s) {
      unsigned long long outv[9];
      int i = 0, j = 0;
#pragma unroll
      for (int k = 0; k < 9; k++) {
        unsigned long long x = ls9[t][i], y = ls9[t + s][j];
        if (x <= y) { outv[k] = x; i++; } else { outv[k] = y; j++; }
      }
#pragma unroll
      for (int k = 0; k < 9; k++) ls9[t][k] = outv[k];
    }
    __syncthreads();
  }
  if (t < 9) supp[t] = (int)(ls9[0][t] & 0xffffffffu);
  __syncthreads();
  int frow = bfrow[b];
  const float* x = emb + (size_t)frow * DDIM;
  float xnv = xnorm[frow];
  for (int k = 0; k < 9; k++) {
    const float* y = mem + (size_t)supp[k] * DDIM;
    float s = 0.f;
    for (int d = t; d < DDIM; d += 256) s = fmaf(x[d], y[d], s);
    for (int off = 32; off; off >>= 1) s += __shfl_down(s, off, 64);
    if ((t & 63) == 0) fred[t >> 6] = s;
    __syncthreads();
    if (t == 0) {
      float dot = fred[0] + fred[1] + fred[2] + fred[3];
      d3s[k] = sqrtf(fmaxf(xnv - 2.f * dot + ynorm[supp[k]], 0.f));
    }
    __syncthreads();
  }
  if (t == 0) {
    float mx = d3s[0];
    for (int k = 1; k < 9; k++) mx = fmaxf(mx, d3s[k]);
    float sum = 0.f;
    for (int k = 0; k < 9; k++) sum += expf(d3s[k] - mx);
    float w = 1.f - expf(d3s[0] - mx) / sum;
    pred[b] = w * bscore[b];
  }
}

// ---------------- gaussian weights ----------------
__global__ void gauss_kernel(float* __restrict__ g) {
  __shared__ float tmp[KS];
  int t = threadIdx.x;
  if (t < KS) {
    float x = (float)t - (float)(KS - 1) * 0.5f;
    tmp[t] = __expf(-(x * x) / 32.0f);
  }
  __syncthreads();
  if (t == 0) {
    float s = 0.f;
    for (int j = 0; j < KS; j++) s += tmp[j];
    for (int j = 0; j < KS; j++) g[j] = tmp[j] / s;
  }
}

// ---------------- bilinear resize 28 -> 224 ----------------
__global__ __launch_bounds__(256) void resize_kernel(const float* __restrict__ ps,
                                                     float* __restrict__ out) {
  int idx = blockIdx.x * 256 + threadIdx.x;
  if (idx >= NB * HW * HW) return;
  int x = idx % HW, y = (idx / HW) % HW, b = idx / (HW * HW);
  float sx = (x + 0.5f) * 0.125f - 0.5f;
  float sy = (y + 0.5f) * 0.125f - 0.5f;
  int x0 = (int)floorf(sx), y0 = (int)floorf(sy);
  float fx = sx - x0, fy = sy - y0;
  int x0c = min(max(x0, 0), 27), x1c = min(max(x0 + 1, 0), 27);
  int y0c = min(max(y0, 0), 27), y1c = min(max(y0 + 1, 0), 27);
  const float* p = ps + b * PP;
  float v00 = p[y0c * 28 + x0c], v01 = p[y0c * 28 + x1c];
  float v10 = p[y1c * 28 + x0c], v11 = p[y1c * 28 + x1c];
  out[idx] = v00 * (1.f - fy) * (1.f - fx) + v01 * (1.f - fy) * fx +
             v10 * fy * (1.f - fx) + v11 * fy * fx;
}

// ---------------- separable gaussian blur, reflect padding ----------------
__device__ __forceinline__ int reflect224(int i) {
  if (i < 0) i = -i;
  if (i > 223) i = 446 - i;
  return i;
}

__global__ __launch_bounds__(256) void blurv_kernel(const float* __restrict__ in,
                                                    const float* __restrict__ g,
                                                    float* __restrict__ out) {
  __shared__ float gk[KS];
  if (threadIdx.x < KS) gk[threadIdx.x] = g[threadIdx.x];
  __syncthreads();
  int idx = blockIdx.x * 256 + threadIdx.x;
  if (idx >= NB * HW * HW) return;
  int x = idx % HW, y = (idx / HW) % HW, b = idx / (HW * HW);
  const float* base = in + (size_t)b * HW * HW;
  float s = 0.f;
#pragma unroll
  for (int j = 0; j < KS; j++) {
    int yy = reflect224(y - PAD + j);
    s = fmaf(gk[j], base[yy * HW + x], s);
  }
  out[idx] = s;
}

__global__ __launch_bounds__(256) void blurh_kernel(const float* __restrict__ in,
                                                    const float* __restrict__ g,
                                                    float* __restrict__ out) {
  __shared__ float gk[KS];
  if (threadIdx.x < KS) gk[threadIdx.x] = g[threadIdx.x];
  __syncthreads();
  int idx = blockIdx.x * 256 + threadIdx.x;
  if (idx >= NB * HW * HW) return;
  int x = idx % HW, y = (idx / HW) % HW, b = idx / (HW * HW);
  const float* base = in + (size_t)b * HW * HW;
  float s = 0.f;
#pragma unroll
  for (int j = 0; j < KS; j++) {
    int xx = reflect224(x - PAD + j);
    s = fmaf(gk[j], base[y * HW + xx], s);
  }
  out[idx] = s;
}

// ---------------- host ----------------
extern "C" void kernel_launch(void* const* d_in, const int* in_sizes, int n_in,
                              void* d_out, int out_size, void* d_ws, size_t ws_size,
                              hipStream_t stream) {
  const float* emb = (const float*)d_in[0];
  const float* mem = (const float*)d_in[1];
  float* out = (float*)d_out;

  char* ws = (char*)d_ws;
  size_t off = 0;
  auto alloc = [&](size_t bytes) -> void* {
    void* p = ws + off;
    off += (bytes + 255) & ~(size_t)255;
    return p;
  };
  float* ynorm = (float*)alloc((size_t)NCOLPAD * 4);
  float* xnorm = (float*)alloc((size_t)NROWPAD * 4);
  unsigned long long* cand =
      (unsigned long long*)alloc((size_t)NROWS * NCT * 8);
  float* ps = (float*)alloc(NROWS * 4);
  int* loc = (int*)alloc(NROWS * 4);
  float* bscore = (float*)alloc(NB * 4);
  int* bfrow = (int*)alloc(NB * 4);
  int* bnn = (int*)alloc(NB * 4);
  float* d2 = (float*)alloc((size_t)NB * MBANK * 4);
  float* g = (float*)alloc(KS * 4);
  float* rsz = (float*)alloc((size_t)NB * HW * HW * 4);
  float* tmp = (float*)alloc((size_t)NB * HW * HW * 4);
  unsigned short* emb_h = (unsigned short*)alloc((size_t)NROWPAD * DDIM * 2);
  unsigned short* mem_h = (unsigned short*)alloc((size_t)NCOLPAD * DDIM * 2);
  size_t full_need = off;

  bool fast = (ws_size >= full_need);

  if (fast) {
    convnorm_kernel<<<NCOLPAD / 4, 256, 0, stream>>>(mem, mem_h, ynorm, MBANK, NCOLPAD);
    convnorm_kernel<<<NROWPAD / 4, 256, 0, stream>>>(emb, emb_h, xnorm, NROWS, NROWPAD);
    init_u64_kernel<<<(NROWS * NCT + 255) / 256, 256, 0, stream>>>(cand, NROWS * NCT);
    mindist_mfma_kernel<<<NRT * NCT, 256, 0, stream>>>(emb_h, mem_h, xnorm, ynorm, cand);
    rerank_kernel<<<NROWS, 256, 0, stream>>>(emb, mem, xnorm, ynorm, cand, ps, loc);
    argmax_kernel<<<NB, 256, 0, stream>>>(ps, loc, bscore, bfrow, bnn);
  } else {
    rownorm_kernel<<<MBANK, 256, 0, stream>>>(mem, ynorm, MBANK);
    rownorm_kernel<<<NROWS, 256, 0, stream>>>(emb, xnorm, NROWS);
    unsigned long long* best = cand;  // alias
    init_u64_kernel<<<(NROWS + 255) / 256, 256, 0, stream>>>(best, NROWS);
    mindist_kernel<<<dim3(NROWS / BM, FCSPLIT), 256, 0, stream>>>(emb, mem, xnorm, ynorm,
                                                                  best);
    unpack_kernel<<<(NROWS + 255) / 256, 256, 0, stream>>>(best, ps, loc);
    argmax_kernel<<<NB, 256, 0, stream>>>(ps, loc, bscore, bfrow, bnn);
  }

  d2_kernel<<<400, 256, 0, stream>>>(mem, ynorm, bnn, d2);
  topk_kernel<<<NB, 256, 0, stream>>>(emb, mem, xnorm, ynorm, d2, bscore, bfrow,
                                      out + (size_t)NB * HW * HW);
  gauss_kernel<<<1, 64, 0, stream>>>(g);
  resize_kernel<<<(NB * HW * HW + 255) / 256, 256, 0, stream>>>(ps, rsz);
  blurv_kernel<<<(NB * HW * HW + 255) / 256, 256, 0, stream>>>(rsz, g, tmp);
  blurh_kernel<<<(NB * HW * HW + 255) / 256, 256, 0, stream>>>(tmp, g, out);
}